// Round 6
// baseline (4006.750 us; speedup 1.0000x reference)
//
#include <hip/hip_runtime.h>
#include <hip/hip_bf16.h>

// Problem constants
#define B_   4096
#define T_   60
#define TT   30          // pooled sequence length
#define H_   512
#define L_   2
#define NH_  4
#define DH_  128
#define LAT_ 128
#define OUT_ 14
#define NGATE_ (5*H_)    // 2560
#define EPSF 1e-5f
#define KVCHUNK 512      // batch rows per kv chunk (8 chunks)
#define FEATK 64         // feat padded to 64 (GEMM K granularity)

typedef __attribute__((ext_vector_type(8))) short bf16x8;
typedef __attribute__((ext_vector_type(4))) float f32x4;

__device__ __forceinline__ float sigmoidf_(float x) { return 1.0f / (1.0f + __expf(-x)); }

__device__ __forceinline__ void async_load16(const void* g, void* l) {
    __builtin_amdgcn_global_load_lds((const __attribute__((address_space(1))) void*)g,
                                     (__attribute__((address_space(3))) void*)l, 16, 0, 0);
}

// ---------------------------------------------------------------------------
// Utility kernels
// ---------------------------------------------------------------------------
__global__ __launch_bounds__(256) void cvt_bf16(const float* __restrict__ in,
                                                __hip_bfloat16* __restrict__ out, long n) {
    long i = (long)blockIdx.x * blockDim.x + threadIdx.x;
    long stride = (long)gridDim.x * blockDim.x;
    for (; i < n; i += stride) out[i] = __float2bfloat16(in[i]);
}

__global__ __launch_bounds__(256) void zero_f32(float* __restrict__ p, long n) {
    long i = (long)blockIdx.x * blockDim.x + threadIdx.x;
    long stride = (long)gridDim.x * blockDim.x;
    for (; i < n; i += stride) p[i] = 0.0f;
}

// proj_w [512,44] f32 -> padded [512,64] bf16 (cols 44..63 zero)
__global__ __launch_bounds__(256) void pad_projw(const float* __restrict__ pw,
                                                 __hip_bfloat16* __restrict__ out) {
    int i = blockIdx.x * 256 + threadIdx.x;      // 512*64 = 32768
    if (i >= H_ * FEATK) return;
    int r = i >> 6, c = i & 63;
    out[i] = __float2bfloat16(c < 44 ? pw[r * 44 + c] : 0.f);
}

// ---------------------------------------------------------------------------
// Front-end: conv1d(9->24,k3,p1)+relu+bn -> maxpool2 -> concat comp(8->20 relu)
// Writes feat [B*TT, 64] bf16 (cols 44..63 zero). Proj happens via MFMA GEMM.
// ---------------------------------------------------------------------------
__global__ __launch_bounds__(256)
void frontend_kernel(const float* __restrict__ x,
                     const float* __restrict__ cw, const float* __restrict__ cb,
                     const float* __restrict__ bg, const float* __restrict__ bb,
                     const float* __restrict__ brm, const float* __restrict__ brv,
                     const float* __restrict__ compw, const float* __restrict__ compb,
                     __hip_bfloat16* __restrict__ feat_out) {
    const int b = blockIdx.x, tid = threadIdx.x;
    __shared__ float xs[T_ * 17];        // 4080 B
    __shared__ float ybuf[24][T_];       // 5760 B
    __shared__ float feat[TT][44];       // 5280 B

    for (int i = tid; i < T_ * 17; i += 256) xs[i] = x[(long)b * T_ * 17 + i];
    __syncthreads();

    // conv + relu + bn1
    for (int i = tid; i < 24 * T_; i += 256) {
        int oc = i / T_, t = i % T_;
        float acc = cb[oc];
        #pragma unroll
        for (int kk = 0; kk < 3; ++kk) {
            int tt = t + kk - 1;
            if (tt >= 0 && tt < T_) {
                #pragma unroll
                for (int ic = 0; ic < 9; ++ic)
                    acc += xs[tt * 17 + ic] * cw[(oc * 9 + ic) * 3 + kk];
            }
        }
        acc = fmaxf(acc, 0.f);
        acc = (acc - brm[oc]) * rsqrtf(brv[oc] + EPSF) * bg[oc] + bb[oc];
        ybuf[oc][t] = acc;
    }
    __syncthreads();

    // maxpool(2) -> feat[:, :24]
    for (int i = tid; i < TT * 24; i += 256) {
        int u = i / 24, oc = i % 24;
        feat[u][oc] = fmaxf(ybuf[oc][2 * u], ybuf[oc][2 * u + 1]);
    }
    // comp: relu(x[:, :30, 9:17] @ comp_w.T + b) -> feat[:, 24:44]
    for (int i = tid; i < TT * 20; i += 256) {
        int u = i / 20, oc = i % 20;
        float acc = compb[oc];
        #pragma unroll
        for (int j = 0; j < 8; ++j) acc += xs[u * 17 + 9 + j] * compw[oc * 8 + j];
        feat[u][24 + oc] = fmaxf(acc, 0.f);
    }
    __syncthreads();

    // write padded bf16 feat rows
    for (int i = tid; i < TT * FEATK; i += 256) {
        int u = i >> 6, c = i & 63;
        float v = (c < 44) ? feat[u][c] : 0.f;
        feat_out[((long)b * TT + u) * FEATK + c] = __float2bfloat16(v);
    }
}

// ---------------------------------------------------------------------------
// bf16 MFMA GEMM core: C[m,n] = sum_k A[m,k] * W[n,k] + bias[n]
// A split along K at `ksplit` between A0 (stride lda0) and A1 (stride lda1).
// W has row stride ldw (>= K). 128x128 tile, BK=64, global_load_lds staging.
//
// LDS bank-conflict fix (R5, verified: SQ_LDS_BANK_CONFLICT 1.57e7 -> 0):
// LDS slot (row, c) holds global K-chunk c ^ (row&7); permutation applied on
// the global SOURCE address (LDS dest of global_load_lds is forced
// contiguous). Reads use the matching offset.
//
// R6: epilogue stores are non-temporal — C (the gate buffer) is read exactly
// once, streaming it through L2 would evict the XCD-pinned weight slices.
// ---------------------------------------------------------------------------
template <int WRITE_BF16>
__device__ __forceinline__
void gemm_core(const __hip_bfloat16* __restrict__ A0, int lda0,
               const __hip_bfloat16* __restrict__ A1, int lda1, int ksplit,
               const __hip_bfloat16* __restrict__ W, int ldw,
               const float* __restrict__ bias,
               void* __restrict__ Cout, int ldc, int K, int bx, int by) {
    __shared__ __hip_bfloat16 As[128 * 64];
    __shared__ __hip_bfloat16 Bs[128 * 64];
    const int tid = threadIdx.x;
    const int wave = tid >> 6, lane = tid & 63;
    const long m0 = (long)by * 128;
    const long n0 = (long)bx * 128;

    f32x4 acc[4][4] = {};

    for (int k0 = 0; k0 < K; k0 += 64) {
        __syncthreads();
        #pragma unroll
        for (int it = 0; it < 4; ++it) {
            int id = it * 256 + tid;          // 0..1023 -> 16 B each
            int row = id >> 3;                // 0..127
            int kc = ((id & 7) ^ (row & 7)) << 3;   // swizzled source chunk
            int gk = k0 + kc;
            const __hip_bfloat16* srcA;
            if (gk < ksplit) srcA = A0 + (m0 + row) * (long)lda0 + gk;
            else             srcA = A1 + (m0 + row) * (long)lda1 + (gk - ksplit);
            async_load16(srcA, &As[id * 8]);
            const __hip_bfloat16* srcB = W + (n0 + row) * (long)ldw + gk;
            async_load16(srcB, &Bs[id * 8]);
        }
        __syncthreads();
        #pragma unroll
        for (int ks = 0; ks < 2; ++ks) {
            const int kb = ((ks * 4 + (lane >> 4)) ^ (lane & 7)) << 3;
            const int ar = (wave >> 1) * 64 + (lane & 15);
            const int br = (wave & 1) * 64 + (lane & 15);
            bf16x8 afr[4], bfr[4];
            #pragma unroll
            for (int i = 0; i < 4; ++i) afr[i] = *(const bf16x8*)&As[(ar + i * 16) * 64 + kb];
            #pragma unroll
            for (int i = 0; i < 4; ++i) bfr[i] = *(const bf16x8*)&Bs[(br + i * 16) * 64 + kb];
            #pragma unroll
            for (int mi = 0; mi < 4; ++mi)
                #pragma unroll
                for (int ni = 0; ni < 4; ++ni)
                    acc[mi][ni] = __builtin_amdgcn_mfma_f32_16x16x32_bf16(afr[mi], bfr[ni], acc[mi][ni], 0, 0, 0);
        }
    }

    // epilogue: C/D layout col=lane&15, row=(lane>>4)*4+r ; non-temporal
    const int cr = (lane >> 4) * 4;
    const int ccol = lane & 15;
    #pragma unroll
    for (int ni = 0; ni < 4; ++ni) {
        long col = n0 + (wave & 1) * 64 + ni * 16 + ccol;
        float bv = bias ? bias[col] : 0.f;
        #pragma unroll
        for (int mi = 0; mi < 4; ++mi) {
            long rowb = m0 + (wave >> 1) * 64 + mi * 16 + cr;
            #pragma unroll
            for (int r = 0; r < 4; ++r) {
                float v = acc[mi][ni][r] + bv;
                if (WRITE_BF16) {
                    __hip_bfloat16 hv = __float2bfloat16(v);
                    __builtin_nontemporal_store(*(short*)&hv,
                        (short*)Cout + (rowb + r) * (long)ldc + col);
                } else {
                    __builtin_nontemporal_store(v,
                        (float*)Cout + (rowb + r) * (long)ldc + col);
                }
            }
        }
    }
}

template <int WRITE_BF16>
__global__ __launch_bounds__(256)
void gemm_bias(const __hip_bfloat16* __restrict__ A0, int lda0,
               const __hip_bfloat16* __restrict__ A1, int lda1, int ksplit,
               const __hip_bfloat16* __restrict__ W, int ldw,
               const float* __restrict__ bias,
               void* __restrict__ Cout, int ldc, int K) {
    gemm_core<WRITE_BF16>(A0, lda0, A1, lda1, ksplit, W, ldw, bias, Cout, ldc, K,
                          blockIdx.x, blockIdx.y);
}

// ---------------------------------------------------------------------------
// Dual-problem gate GEMM with XCD-pinned weight slices (R6).
// 1D grid of 1280 blocks; dispatch round-robins id%8 across the 8 XCDs, so
// decode id st. all 32 m-blocks of a given (col,z) weight slice land on ONE
// XCD: per-XCD weight footprint = 5 slices x 256 KB = 1.28 MB -> L2-resident
// across m-blocks AND across scan dispatches.
//   id = xcd + 8*(m + 32*pgrp), pgrp in [0,5): p = xcd + 8*pgrp in [0,40)
//   col = p % 20, z = p / 20, m in [0,32)
// ---------------------------------------------------------------------------
template <int WRITE_BF16>
__global__ __launch_bounds__(256)
void gemm_bias_dual_x(const __hip_bfloat16* A0a, int lda0a, const __hip_bfloat16* A1a,
                      int lda1a, int Ka, const __hip_bfloat16* Wa,
                      const float* biasa, void* Ca,
                      const __hip_bfloat16* A0b, int lda0b, const __hip_bfloat16* A1b,
                      int lda1b, int Kb, const __hip_bfloat16* Wb,
                      const float* biasb, void* Cb,
                      int ksplit, int ldw, int ldc) {
    const int id = blockIdx.x;
    const int xcd = id & 7;
    const int rest = id >> 3;
    const int m = rest & 31;
    const int pgrp = rest >> 5;
    const int p = xcd + 8 * pgrp;      // 0..39
    const int col = p % 20;
    const int z = p / 20;
    const __hip_bfloat16* A0 = z ? A0b : A0a;
    const __hip_bfloat16* A1 = z ? A1b : A1a;
    const __hip_bfloat16* W  = z ? Wb  : Wa;
    const float* bias        = z ? biasb : biasa;
    void* Cout               = z ? Cb : Ca;
    int lda0 = z ? lda0b : lda0a;
    int lda1 = z ? lda1b : lda1a;
    int K    = z ? Kb : Ka;
    gemm_core<WRITE_BF16>(A0, lda0, A1, lda1, ksplit, W, ldw, bias, Cout, ldc, K,
                          col, m);
}

// ---------------------------------------------------------------------------
// Gate elementwise + the two LayerNorms. One block (256 thr) per batch row.
// g: [B, 2560] bf16 (f,i,o,cc,m blocks of 512). c: [B,512] f32 (updated).
// ---------------------------------------------------------------------------
__device__ __forceinline__ void block_reduce2(float& a, float& b, float* red) {
    #pragma unroll
    for (int off = 32; off > 0; off >>= 1) {
        a += __shfl_down(a, off, 64);
        b += __shfl_down(b, off, 64);
    }
    int lane = threadIdx.x & 63, w = threadIdx.x >> 6;
    if (lane == 0) { red[w] = a; red[8 + w] = b; }
    __syncthreads();
    a = red[0] + red[1] + red[2] + red[3];
    b = red[8] + red[9] + red[10] + red[11];
    __syncthreads();
}

__device__ __forceinline__
void gate_ew_body(const __hip_bfloat16* __restrict__ g, float* __restrict__ c,
                  const float* __restrict__ ret,
                  const float* __restrict__ elg, const float* __restrict__ elb,
                  const float* __restrict__ lng, const float* __restrict__ lnb,
                  __hip_bfloat16* __restrict__ hout, long hstride, int b) {
    const int tid = threadIdx.x;
    const __hip_bfloat16* gr = g + (long)b * NGATE_;
    __shared__ float red[16];

    float o_[2], cn_[2];
    float s = 0.f, s2 = 0.f;
    #pragma unroll
    for (int u = 0; u < 2; ++u) {
        int j = tid + u * 256;
        float fg = __bfloat162float(gr[j]);
        float ig = __bfloat162float(gr[512 + j]);
        float og = __bfloat162float(gr[1024 + j]);
        float cg = __bfloat162float(gr[1536 + j]);
        float mg = __bfloat162float(gr[2048 + j]);
        float f = sigmoidf_(fg), i = sigmoidf_(ig), o = sigmoidf_(og);
        float cc = tanhf(cg), m = sigmoidf_(mg);
        float cold = c[(long)b * H_ + j];
        float r = ret[j];
        float cn = f * cold + i * cc;
        cn = cn * r + (1.f - r) * cold;
        cn = m * cn + (1.f - m) * cold;
        c[(long)b * H_ + j] = cn;
        o_[u] = o; cn_[u] = cn;
        s += o; s2 += o * o;
    }
    block_reduce2(s, s2, red);
    float mean = s * (1.f / H_);
    float var = s2 * (1.f / H_) - mean * mean;
    float rstd = rsqrtf(var + EPSF);

    float val[2];
    float s3 = 0.f, s4 = 0.f;
    #pragma unroll
    for (int u = 0; u < 2; ++u) {
        int j = tid + u * 256;
        float on = (o_[u] - mean) * rstd * elg[j] + elb[j];
        float oe = sigmoidf_(on);
        float v = oe * tanhf(cn_[u]);
        val[u] = v; s3 += v; s4 += v * v;
    }
    block_reduce2(s3, s4, red);
    float mean2 = s3 * (1.f / H_);
    float var2 = s4 * (1.f / H_) - mean2 * mean2;
    float rstd2 = rsqrtf(var2 + EPSF);
    #pragma unroll
    for (int u = 0; u < 2; ++u) {
        int j = tid + u * 256;
        float h = (val[u] - mean2) * rstd2 * lng[j] + lnb[j];
        hout[(long)b * hstride + j] = __float2bfloat16(h);
    }
}

__global__ __launch_bounds__(256)
void gate_ew(const __hip_bfloat16* __restrict__ g, float* __restrict__ c,
             const float* __restrict__ ret,
             const float* __restrict__ elg, const float* __restrict__ elb,
             const float* __restrict__ lng, const float* __restrict__ lnb,
             __hip_bfloat16* __restrict__ hout, long hstride) {
    gate_ew_body(g, c, ret, elg, elb, lng, lnb, hout, hstride, blockIdx.x);
}

// Dual elementwise: blocks [0,B) run problem A, [B,2B) problem B.
__global__ __launch_bounds__(256)
void gate_ew_dual(const __hip_bfloat16* ga, float* ca, const float* reta,
                  const float* elga, const float* elba,
                  const float* lnga, const float* lnba,
                  __hip_bfloat16* houta, long hstridea,
                  const __hip_bfloat16* gb, float* cb, const float* retb,
                  const float* elgb, const float* elbb,
                  const float* lngb, const float* lnbb,
                  __hip_bfloat16* houtb, long hstrideb) {
    int bid = blockIdx.x;
    bool isB = bid >= B_;
    int b = isB ? bid - B_ : bid;
    const __hip_bfloat16* g = isB ? gb : ga;
    float* c        = isB ? cb : ca;
    const float* ret = isB ? retb : reta;
    const float* elg = isB ? elgb : elga;
    const float* elb = isB ? elbb : elba;
    const float* lng = isB ? lngb : lnga;
    const float* lnb = isB ? lnbb : lnba;
    __hip_bfloat16* hout = isB ? houtb : houta;
    long hstride = isB ? hstrideb : hstridea;
    gate_ew_body(g, c, ret, elg, elb, lng, lnb, hout, hstride, b);
}

// ---------------------------------------------------------------------------
// Attention for the last query only. One wave per (b, head), b chunk-local.
// kv: [KVCHUNK*30, 1024] bf16, cols 0..511 = k, 512..1023 = v.
// ---------------------------------------------------------------------------
__global__ __launch_bounds__(64)
void attn_kernel(const float* __restrict__ q, const __hip_bfloat16* __restrict__ kv,
                 __hip_bfloat16* __restrict__ outv) {
    const int bh = blockIdx.x;
    const int b = bh >> 2, h = bh & 3;
    const int l = threadIdx.x;
    const float scale = 0.0883883476483184f;  // 1/sqrt(128)
    float q0 = q[(long)b * H_ + h * DH_ + l];
    float q1 = q[(long)b * H_ + h * DH_ + 64 + l];
    __shared__ float p[32];
    for (int t = 0; t < TT; ++t) {
        const __hip_bfloat16* kp = kv + ((long)b * TT + t) * 1024 + h * DH_;
        float s = q0 * __bfloat162float(kp[l]) + q1 * __bfloat162float(kp[64 + l]);
        #pragma unroll
        for (int o = 32; o > 0; o >>= 1) s += __shfl_down(s, o, 64);
        if (l == 0) p[t] = s * scale;
    }
    __syncthreads();
    float mx = -1e30f;
    for (int t = 0; t < TT; ++t) mx = fmaxf(mx, p[t]);
    float den = 0.f;
    for (int t = 0; t < TT; ++t) den += __expf(p[t] - mx);
    float a0 = 0.f, a1 = 0.f;
    for (int t = 0; t < TT; ++t) {
        float wt = __expf(p[t] - mx);
        const __hip_bfloat16* vp = kv + ((long)b * TT + t) * 1024 + 512 + h * DH_;
        a0 += wt * __bfloat162float(vp[l]);
        a1 += wt * __bfloat162float(vp[64 + l]);
    }
    float inv = 1.f / den;
    outv[(long)b * H_ + h * DH_ + l] = __float2bfloat16(a0 * inv);
    outv[(long)b * H_ + h * DH_ + 64 + l] = __float2bfloat16(a1 * inv);
}

// ---------------------------------------------------------------------------
// Head: bn2 on latent then out (128->14). One block (128 thr) per batch row.
// ---------------------------------------------------------------------------
__global__ __launch_bounds__(128)
void head_kernel(const float* __restrict__ lat_in,
                 const float* __restrict__ g2, const float* __restrict__ b2,
                 const float* __restrict__ rm2, const float* __restrict__ rv2,
                 const float* __restrict__ ow, const float* __restrict__ ob,
                 float* __restrict__ out) {
    const int b = blockIdx.x, tid = threadIdx.x;
    __shared__ float ls[LAT_];
    float a = lat_in[(long)b * LAT_ + tid];
    ls[tid] = (a - rm2[tid]) * rsqrtf(rv2[tid] + EPSF) * g2[tid] + b2[tid];
    __syncthreads();
    if (tid < OUT_) {
        float acc = ob[tid];
        #pragma unroll 4
        for (int j = 0; j < LAT_; ++j) acc += ls[j] * ow[tid * LAT_ + j];
        out[(long)b * OUT_ + tid] = acc;
    }
}

// ---------------------------------------------------------------------------
extern "C" void kernel_launch(void* const* d_in, const int* in_sizes, int n_in,
                              void* d_out, int out_size, void* d_ws, size_t ws_size,
                              hipStream_t stream) {
    const float* x        = (const float*)d_in[0];
    const float* conv1_w  = (const float*)d_in[1];
    const float* conv1_b  = (const float*)d_in[2];
    const float* bn1_g    = (const float*)d_in[3];
    const float* bn1_b    = (const float*)d_in[4];
    const float* bn1_rm   = (const float*)d_in[5];
    const float* bn1_rv   = (const float*)d_in[6];
    const float* comp_w   = (const float*)d_in[7];
    const float* comp_b   = (const float*)d_in[8];
    const float* proj_w   = (const float*)d_in[9];
    const float* proj_b   = (const float*)d_in[10];
    const float* gates_w  = (const float*)d_in[11];
    const float* gates_b  = (const float*)d_in[12];
    const float* retention= (const float*)d_in[13];
    const float* expln_g  = (const float*)d_in[14];
    const float* expln_b  = (const float*)d_in[15];
    const float* ln_g     = (const float*)d_in[16];
    const float* ln_b     = (const float*)d_in[17];
    const float* attn_in_w  = (const float*)d_in[18];
    const float* attn_in_b  = (const float*)d_in[19];
    const float* attn_out_w = (const float*)d_in[20];
    const float* attn_out_b = (const float*)d_in[21];
    const float* bneck_w  = (const float*)d_in[22];
    const float* bneck_b  = (const float*)d_in[23];
    const float* bn2_g    = (const float*)d_in[24];
    const float* bn2_b    = (const float*)d_in[25];
    const float* bn2_rm   = (const float*)d_in[26];
    const float* bn2_rv   = (const float*)d_in[27];
    const float* out_w    = (const float*)d_in[28];
    const float* out_b    = (const float*)d_in[29];
    float* out = (float*)d_out;

    // ---- compact workspace layout (~218 MiB total) ----
    char* base = (char*)d_ws;
    size_t off = 0;
    auto alloc = [&](size_t nbytes) -> char* {
        char* p = base + off;
        off += (nbytes + 255) & ~(size_t)255;
        return p;
    };
    __hip_bfloat16* seq_bf = (__hip_bfloat16*)alloc((size_t)B_ * TT * H_ * 2);   // 126 MB
    // union: feat (front-end) / 2x bf16 gate buffers (scan) / kv chunk (attn)
    size_t g_bytes    = (size_t)B_ * NGATE_ * 2;                                 // 21 MB
    size_t kv_bytes   = (size_t)KVCHUNK * TT * 1024 * 2;                         // 31.4 MB
    size_t un_bytes   = 2 * g_bytes;                                             // 42 MB (max)
    char* un = alloc(un_bytes);
    __hip_bfloat16* feat_bf = (__hip_bfloat16*)un;
    __hip_bfloat16* gA_bf   = (__hip_bfloat16*)un;                 // layer-1 gates
    __hip_bfloat16* gB_bf   = (__hip_bfloat16*)(un + g_bytes);     // layer-0 gates
    __hip_bfloat16* kv_bf   = (__hip_bfloat16*)un;
    (void)kv_bytes;
    float*          c0    = (float*)alloc((size_t)B_ * H_ * 4);   // c0,c1 contiguous
    float*          c1    = (float*)alloc((size_t)B_ * H_ * 4);
    __hip_bfloat16* h0_bf = (__hip_bfloat16*)alloc((size_t)B_ * H_ * 2);
    float*          q_f   = (float*)alloc((size_t)B_ * H_ * 4);   // reused as fin_bf
    __hip_bfloat16* fin_bf = (__hip_bfloat16*)q_f;
    __hip_bfloat16* av_bf = (__hip_bfloat16*)alloc((size_t)B_ * H_ * 2);
    float*          lat_f = (float*)alloc((size_t)B_ * LAT_ * 4); // 2.1 MB
    __hip_bfloat16* gw_bf = (__hip_bfloat16*)alloc((size_t)L_ * 5 * H_ * 2 * H_ * 2);
    __hip_bfloat16* ai_bf = (__hip_bfloat16*)alloc((size_t)3 * H_ * H_ * 2);
    __hip_bfloat16* ao_bf = (__hip_bfloat16*)alloc((size_t)H_ * H_ * 2);
    __hip_bfloat16* pw_bf = (__hip_bfloat16*)alloc((size_t)H_ * FEATK * 2);
    __hip_bfloat16* bw_bf = (__hip_bfloat16*)alloc((size_t)LAT_ * H_ * 2);
    (void)ws_size; (void)in_sizes; (void)n_in; (void)out_size;

    // ---- weight conversion + state zeroing ----
    cvt_bf16<<<2048, 256, 0, stream>>>(gates_w, gw_bf, (long)L_ * 5 * H_ * 2 * H_);
    cvt_bf16<<<512, 256, 0, stream>>>(attn_in_w, ai_bf, (long)3 * H_ * H_);
    cvt_bf16<<<256, 256, 0, stream>>>(attn_out_w, ao_bf, (long)H_ * H_);
    cvt_bf16<<<64, 256, 0, stream>>>(bneck_w, bw_bf, (long)LAT_ * H_);
    pad_projw<<<(H_ * FEATK + 255) / 256, 256, 0, stream>>>(proj_w, pw_bf);
    zero_f32<<<2048, 256, 0, stream>>>(c0, (long)2 * B_ * H_);   // c0+c1 contiguous

    // ---- front-end: feat, then proj via MFMA GEMM ----
    frontend_kernel<<<B_, 256, 0, stream>>>(x, conv1_w, conv1_b, bn1_g, bn1_b, bn1_rm,
                                            bn1_rv, comp_w, comp_b, feat_bf);
    gemm_bias<1><<<dim3(H_ / 128, (B_ * TT) / 128), 256, 0, stream>>>(
        feat_bf, FEATK, (const __hip_bfloat16*)nullptr, 0, FEATK,
        pw_bf, FEATK, proj_b, (void*)seq_bf, H_, FEATK);

    // ---- recurrent scan (software-pipelined: layer1(t) || layer0(t+1)) ----
    const int WL = 5 * H_ * 2 * H_;  // weight elems per layer
    const dim3 ggrid(NGATE_ / 128, B_ / 128);

    // prologue: layer0 step 0 (h0==0 -> K=512 prefix)
    gemm_bias<1><<<ggrid, 256, 0, stream>>>(
        seq_bf, TT * H_, (const __hip_bfloat16*)nullptr, 0, H_,
        gw_bf, 2 * H_, gates_b, (void*)gB_bf, NGATE_, H_);
    gate_ew<<<B_, 256, 0, stream>>>(gB_bf, c0, retention, expln_g, expln_b,
                                    ln_g, ln_b, h0_bf, H_);

    for (int t = 0; t < TT - 1; ++t) {
        // problem A: layer1(t)  [t=0: h1 prev == 0 -> K=512 prefix]
        // problem B: layer0(t+1)
        gemm_bias_dual_x<1><<<1280, 256, 0, stream>>>(
            h0_bf, H_, (t == 0) ? (const __hip_bfloat16*)nullptr
                                : seq_bf + (size_t)(t - 1) * H_,
            TT * H_, (t == 0) ? H_ : 2 * H_, gw_bf + WL, gates_b + NGATE_, (void*)gA_bf,
            seq_bf + (size_t)(t + 1) * H_, TT * H_, h0_bf, H_, 2 * H_,
            gw_bf, gates_b, (void*)gB_bf,
            H_, 2 * H_, NGATE_);
        gate_ew_dual<<<2 * B_, 256, 0, stream>>>(
            gA_bf, c1, retention + H_, expln_g + H_, expln_b + H_,
            ln_g + H_, ln_b + H_, seq_bf + (size_t)t * H_, TT * H_,
            gB_bf, c0, retention, expln_g, expln_b,
            ln_g, ln_b, h0_bf, H_);
    }
    // epilogue: layer1 step 29
    gemm_bias<1><<<ggrid, 256, 0, stream>>>(
        h0_bf, H_, seq_bf + (size_t)(TT - 2) * H_, TT * H_, H_,
        gw_bf + WL, 2 * H_, gates_b + NGATE_, (void*)gA_bf, NGATE_, 2 * H_);
    gate_ew<<<B_, 256, 0, stream>>>(gA_bf, c1, retention + H_, expln_g + H_,
                                    expln_b + H_, ln_g + H_, ln_b + H_,
                                    seq_bf + (size_t)(TT - 1) * H_, TT * H_);

    // ---- q projection (last timestep only) ----
    gemm_bias<0><<<dim3(H_ / 128, B_ / 128), 256, 0, stream>>>(
        seq_bf + (size_t)29 * H_, TT * H_, (const __hip_bfloat16*)nullptr, 0, H_,
        ai_bf, H_, attn_in_b, (void*)q_f, H_, H_);

    // ---- kv projection + attention, in 8 batch chunks of KVCHUNK rows ----
    for (int bc = 0; bc < B_ / KVCHUNK; ++bc) {
        const __hip_bfloat16* seq_c = seq_bf + (size_t)bc * KVCHUNK * TT * H_;
        gemm_bias<1><<<dim3(1024 / 128, (KVCHUNK * TT) / 128), 256, 0, stream>>>(
            seq_c, H_, (const __hip_bfloat16*)nullptr, 0, H_,
            ai_bf + (size_t)H_ * H_, H_, attn_in_b + H_, (void*)kv_bf, 2 * H_, H_);
        attn_kernel<<<KVCHUNK * NH_, 64, 0, stream>>>(
            q_f + (size_t)bc * KVCHUNK * H_, kv_bf, av_bf + (size_t)bc * KVCHUNK * H_);
    }

    // ---- attn_out projection -> bf16 fin (aliases q_f; q fully consumed) ----
    gemm_bias<1><<<dim3(H_ / 128, B_ / 128), 256, 0, stream>>>(
        av_bf, H_, (const __hip_bfloat16*)nullptr, 0, H_,
        ao_bf, H_, attn_out_b, (void*)fin_bf, H_, H_);

    // ---- bneck via MFMA GEMM -> latent f32, then bn2+head ----
    gemm_bias<0><<<dim3(LAT_ / 128, B_ / 128), 256, 0, stream>>>(
        fin_bf, H_, (const __hip_bfloat16*)nullptr, 0, H_,
        bw_bf, H_, bneck_b, (void*)lat_f, LAT_, H_);
    head_kernel<<<B_, 128, 0, stream>>>(lat_f, bn2_g, bn2_b, bn2_rm, bn2_rv,
                                        out_w, out_b, out);
}

// Round 7
// 3351.516 us; speedup vs baseline: 1.1955x; 1.1955x over previous
//
#include <hip/hip_runtime.h>
#include <hip/hip_bf16.h>

// Problem constants
#define B_   4096
#define T_   60
#define TT   30          // pooled sequence length
#define H_   512
#define L_   2
#define NH_  4
#define DH_  128
#define LAT_ 128
#define OUT_ 14
#define NGATE_ (5*H_)    // 2560
#define EPSF 1e-5f
#define KVCHUNK 512      // batch rows per kv chunk (8 chunks)
#define FEATK 64         // feat padded to 64 (GEMM K granularity)

typedef __attribute__((ext_vector_type(8))) short bf16x8;
typedef __attribute__((ext_vector_type(4))) float f32x4;

__device__ __forceinline__ float sigmoidf_(float x) { return 1.0f / (1.0f + __expf(-x)); }

__device__ __forceinline__ void async_load16(const void* g, void* l) {
    __builtin_amdgcn_global_load_lds((const __attribute__((address_space(1))) void*)g,
                                     (__attribute__((address_space(3))) void*)l, 16, 0, 0);
}

// ---------------------------------------------------------------------------
// Utility kernels
// ---------------------------------------------------------------------------
__global__ __launch_bounds__(256) void cvt_bf16(const float* __restrict__ in,
                                                __hip_bfloat16* __restrict__ out, long n) {
    long i = (long)blockIdx.x * blockDim.x + threadIdx.x;
    long stride = (long)gridDim.x * blockDim.x;
    for (; i < n; i += stride) out[i] = __float2bfloat16(in[i]);
}

__global__ __launch_bounds__(256) void zero_f32(float* __restrict__ p, long n) {
    long i = (long)blockIdx.x * blockDim.x + threadIdx.x;
    long stride = (long)gridDim.x * blockDim.x;
    for (; i < n; i += stride) p[i] = 0.0f;
}

// proj_w [512,44] f32 -> padded [512,64] bf16 (cols 44..63 zero)
__global__ __launch_bounds__(256) void pad_projw(const float* __restrict__ pw,
                                                 __hip_bfloat16* __restrict__ out) {
    int i = blockIdx.x * 256 + threadIdx.x;      // 512*64 = 32768
    if (i >= H_ * FEATK) return;
    int r = i >> 6, c = i & 63;
    out[i] = __float2bfloat16(c < 44 ? pw[r * 44 + c] : 0.f);
}

// ---------------------------------------------------------------------------
// Front-end: conv1d(9->24,k3,p1)+relu+bn -> maxpool2 -> concat comp(8->20 relu)
// Writes feat [B*TT, 64] bf16 (cols 44..63 zero). Proj happens via MFMA GEMM.
// ---------------------------------------------------------------------------
__global__ __launch_bounds__(256)
void frontend_kernel(const float* __restrict__ x,
                     const float* __restrict__ cw, const float* __restrict__ cb,
                     const float* __restrict__ bg, const float* __restrict__ bb,
                     const float* __restrict__ brm, const float* __restrict__ brv,
                     const float* __restrict__ compw, const float* __restrict__ compb,
                     __hip_bfloat16* __restrict__ feat_out) {
    const int b = blockIdx.x, tid = threadIdx.x;
    __shared__ float xs[T_ * 17];        // 4080 B
    __shared__ float ybuf[24][T_];       // 5760 B
    __shared__ float feat[TT][44];       // 5280 B

    for (int i = tid; i < T_ * 17; i += 256) xs[i] = x[(long)b * T_ * 17 + i];
    __syncthreads();

    // conv + relu + bn1
    for (int i = tid; i < 24 * T_; i += 256) {
        int oc = i / T_, t = i % T_;
        float acc = cb[oc];
        #pragma unroll
        for (int kk = 0; kk < 3; ++kk) {
            int tt = t + kk - 1;
            if (tt >= 0 && tt < T_) {
                #pragma unroll
                for (int ic = 0; ic < 9; ++ic)
                    acc += xs[tt * 17 + ic] * cw[(oc * 9 + ic) * 3 + kk];
            }
        }
        acc = fmaxf(acc, 0.f);
        acc = (acc - brm[oc]) * rsqrtf(brv[oc] + EPSF) * bg[oc] + bb[oc];
        ybuf[oc][t] = acc;
    }
    __syncthreads();

    // maxpool(2) -> feat[:, :24]
    for (int i = tid; i < TT * 24; i += 256) {
        int u = i / 24, oc = i % 24;
        feat[u][oc] = fmaxf(ybuf[oc][2 * u], ybuf[oc][2 * u + 1]);
    }
    // comp: relu(x[:, :30, 9:17] @ comp_w.T + b) -> feat[:, 24:44]
    for (int i = tid; i < TT * 20; i += 256) {
        int u = i / 20, oc = i % 20;
        float acc = compb[oc];
        #pragma unroll
        for (int j = 0; j < 8; ++j) acc += xs[u * 17 + 9 + j] * compw[oc * 8 + j];
        feat[u][24 + oc] = fmaxf(acc, 0.f);
    }
    __syncthreads();

    // write padded bf16 feat rows
    for (int i = tid; i < TT * FEATK; i += 256) {
        int u = i >> 6, c = i & 63;
        float v = (c < 44) ? feat[u][c] : 0.f;
        feat_out[((long)b * TT + u) * FEATK + c] = __float2bfloat16(v);
    }
}

// ---------------------------------------------------------------------------
// bf16 MFMA GEMM core: C[m,n] = sum_k A[m,k] * W[n,k] + bias[n]
// A split along K at `ksplit` between A0 (stride lda0) and A1 (stride lda1).
// W has row stride ldw (>= K). 128x128 tile, BK=64, global_load_lds staging.
//
// LDS bank-conflict fix (R5, verified: SQ_LDS_BANK_CONFLICT 1.57e7 -> 0):
// LDS slot (row, c) holds global K-chunk c ^ (row&7); permutation applied on
// the global SOURCE address (LDS dest of global_load_lds is forced
// contiguous). Reads use the matching offset.
//
// R7: plain epilogue stores. R6's __builtin_nontemporal_store of scattered
// 2-byte bf16 bypassed L2 write-combining -> partial-line HBM RMW, 1.35x
// write amplification, proj GEMM 127 us (MfmaUtil 2.3%). L2 IS the write
// combiner for this epilogue pattern — never NT-store scattered narrow data.
// ---------------------------------------------------------------------------
template <int WRITE_BF16>
__device__ __forceinline__
void gemm_core(const __hip_bfloat16* __restrict__ A0, int lda0,
               const __hip_bfloat16* __restrict__ A1, int lda1, int ksplit,
               const __hip_bfloat16* __restrict__ W, int ldw,
               const float* __restrict__ bias,
               void* __restrict__ Cout, int ldc, int K, int bx, int by) {
    __shared__ __hip_bfloat16 As[128 * 64];
    __shared__ __hip_bfloat16 Bs[128 * 64];
    const int tid = threadIdx.x;
    const int wave = tid >> 6, lane = tid & 63;
    const long m0 = (long)by * 128;
    const long n0 = (long)bx * 128;

    f32x4 acc[4][4] = {};

    for (int k0 = 0; k0 < K; k0 += 64) {
        __syncthreads();
        #pragma unroll
        for (int it = 0; it < 4; ++it) {
            int id = it * 256 + tid;          // 0..1023 -> 16 B each
            int row = id >> 3;                // 0..127
            int kc = ((id & 7) ^ (row & 7)) << 3;   // swizzled source chunk
            int gk = k0 + kc;
            const __hip_bfloat16* srcA;
            if (gk < ksplit) srcA = A0 + (m0 + row) * (long)lda0 + gk;
            else             srcA = A1 + (m0 + row) * (long)lda1 + (gk - ksplit);
            async_load16(srcA, &As[id * 8]);
            const __hip_bfloat16* srcB = W + (n0 + row) * (long)ldw + gk;
            async_load16(srcB, &Bs[id * 8]);
        }
        __syncthreads();
        #pragma unroll
        for (int ks = 0; ks < 2; ++ks) {
            const int kb = ((ks * 4 + (lane >> 4)) ^ (lane & 7)) << 3;
            const int ar = (wave >> 1) * 64 + (lane & 15);
            const int br = (wave & 1) * 64 + (lane & 15);
            bf16x8 afr[4], bfr[4];
            #pragma unroll
            for (int i = 0; i < 4; ++i) afr[i] = *(const bf16x8*)&As[(ar + i * 16) * 64 + kb];
            #pragma unroll
            for (int i = 0; i < 4; ++i) bfr[i] = *(const bf16x8*)&Bs[(br + i * 16) * 64 + kb];
            #pragma unroll
            for (int mi = 0; mi < 4; ++mi)
                #pragma unroll
                for (int ni = 0; ni < 4; ++ni)
                    acc[mi][ni] = __builtin_amdgcn_mfma_f32_16x16x32_bf16(afr[mi], bfr[ni], acc[mi][ni], 0, 0, 0);
        }
    }

    // epilogue: C/D layout col=lane&15, row=(lane>>4)*4+r ; plain stores (L2
    // write-combines the scattered 2B/4B pattern into full lines)
    const int cr = (lane >> 4) * 4;
    const int ccol = lane & 15;
    #pragma unroll
    for (int ni = 0; ni < 4; ++ni) {
        long col = n0 + (wave & 1) * 64 + ni * 16 + ccol;
        float bv = bias ? bias[col] : 0.f;
        #pragma unroll
        for (int mi = 0; mi < 4; ++mi) {
            long rowb = m0 + (wave >> 1) * 64 + mi * 16 + cr;
            #pragma unroll
            for (int r = 0; r < 4; ++r) {
                float v = acc[mi][ni][r] + bv;
                if (WRITE_BF16)
                    ((__hip_bfloat16*)Cout)[(rowb + r) * (long)ldc + col] = __float2bfloat16(v);
                else
                    ((float*)Cout)[(rowb + r) * (long)ldc + col] = v;
            }
        }
    }
}

template <int WRITE_BF16>
__global__ __launch_bounds__(256)
void gemm_bias(const __hip_bfloat16* __restrict__ A0, int lda0,
               const __hip_bfloat16* __restrict__ A1, int lda1, int ksplit,
               const __hip_bfloat16* __restrict__ W, int ldw,
               const float* __restrict__ bias,
               void* __restrict__ Cout, int ldc, int K) {
    gemm_core<WRITE_BF16>(A0, lda0, A1, lda1, ksplit, W, ldw, bias, Cout, ldc, K,
                          blockIdx.x, blockIdx.y);
}

// ---------------------------------------------------------------------------
// Dual-problem gate GEMM with XCD-pinned weight slices (R6, kept for clean
// A/B isolation this round). 1D grid of 1280 blocks; dispatch round-robins
// id%8 across the 8 XCDs; decode so all 32 m-blocks of a (col,z) weight
// slice land on ONE XCD: per-XCD weight footprint = 5 x 256 KB = 1.28 MB.
//   id = xcd + 8*(m + 32*pgrp), pgrp in [0,5): p = xcd + 8*pgrp in [0,40)
//   col = p % 20, z = p / 20, m in [0,32)
// ---------------------------------------------------------------------------
template <int WRITE_BF16>
__global__ __launch_bounds__(256)
void gemm_bias_dual_x(const __hip_bfloat16* A0a, int lda0a, const __hip_bfloat16* A1a,
                      int lda1a, int Ka, const __hip_bfloat16* Wa,
                      const float* biasa, void* Ca,
                      const __hip_bfloat16* A0b, int lda0b, const __hip_bfloat16* A1b,
                      int lda1b, int Kb, const __hip_bfloat16* Wb,
                      const float* biasb, void* Cb,
                      int ksplit, int ldw, int ldc) {
    const int id = blockIdx.x;
    const int xcd = id & 7;
    const int rest = id >> 3;
    const int m = rest & 31;
    const int pgrp = rest >> 5;
    const int p = xcd + 8 * pgrp;      // 0..39
    const int col = p % 20;
    const int z = p / 20;
    const __hip_bfloat16* A0 = z ? A0b : A0a;
    const __hip_bfloat16* A1 = z ? A1b : A1a;
    const __hip_bfloat16* W  = z ? Wb  : Wa;
    const float* bias        = z ? biasb : biasa;
    void* Cout               = z ? Cb : Ca;
    int lda0 = z ? lda0b : lda0a;
    int lda1 = z ? lda1b : lda1a;
    int K    = z ? Kb : Ka;
    gemm_core<WRITE_BF16>(A0, lda0, A1, lda1, ksplit, W, ldw, bias, Cout, ldc, K,
                          col, m);
}

// ---------------------------------------------------------------------------
// Gate elementwise + the two LayerNorms. One block (256 thr) per batch row.
// g: [B, 2560] bf16 (f,i,o,cc,m blocks of 512). c: [B,512] f32 (updated).
// ---------------------------------------------------------------------------
__device__ __forceinline__ void block_reduce2(float& a, float& b, float* red) {
    #pragma unroll
    for (int off = 32; off > 0; off >>= 1) {
        a += __shfl_down(a, off, 64);
        b += __shfl_down(b, off, 64);
    }
    int lane = threadIdx.x & 63, w = threadIdx.x >> 6;
    if (lane == 0) { red[w] = a; red[8 + w] = b; }
    __syncthreads();
    a = red[0] + red[1] + red[2] + red[3];
    b = red[8] + red[9] + red[10] + red[11];
    __syncthreads();
}

__device__ __forceinline__
void gate_ew_body(const __hip_bfloat16* __restrict__ g, float* __restrict__ c,
                  const float* __restrict__ ret,
                  const float* __restrict__ elg, const float* __restrict__ elb,
                  const float* __restrict__ lng, const float* __restrict__ lnb,
                  __hip_bfloat16* __restrict__ hout, long hstride, int b) {
    const int tid = threadIdx.x;
    const __hip_bfloat16* gr = g + (long)b * NGATE_;
    __shared__ float red[16];

    float o_[2], cn_[2];
    float s = 0.f, s2 = 0.f;
    #pragma unroll
    for (int u = 0; u < 2; ++u) {
        int j = tid + u * 256;
        float fg = __bfloat162float(gr[j]);
        float ig = __bfloat162float(gr[512 + j]);
        float og = __bfloat162float(gr[1024 + j]);
        float cg = __bfloat162float(gr[1536 + j]);
        float mg = __bfloat162float(gr[2048 + j]);
        float f = sigmoidf_(fg), i = sigmoidf_(ig), o = sigmoidf_(og);
        float cc = tanhf(cg), m = sigmoidf_(mg);
        float cold = c[(long)b * H_ + j];
        float r = ret[j];
        float cn = f * cold + i * cc;
        cn = cn * r + (1.f - r) * cold;
        cn = m * cn + (1.f - m) * cold;
        c[(long)b * H_ + j] = cn;
        o_[u] = o; cn_[u] = cn;
        s += o; s2 += o * o;
    }
    block_reduce2(s, s2, red);
    float mean = s * (1.f / H_);
    float var = s2 * (1.f / H_) - mean * mean;
    float rstd = rsqrtf(var + EPSF);

    float val[2];
    float s3 = 0.f, s4 = 0.f;
    #pragma unroll
    for (int u = 0; u < 2; ++u) {
        int j = tid + u * 256;
        float on = (o_[u] - mean) * rstd * elg[j] + elb[j];
        float oe = sigmoidf_(on);
        float v = oe * tanhf(cn_[u]);
        val[u] = v; s3 += v; s4 += v * v;
    }
    block_reduce2(s3, s4, red);
    float mean2 = s3 * (1.f / H_);
    float var2 = s4 * (1.f / H_) - mean2 * mean2;
    float rstd2 = rsqrtf(var2 + EPSF);
    #pragma unroll
    for (int u = 0; u < 2; ++u) {
        int j = tid + u * 256;
        float h = (val[u] - mean2) * rstd2 * lng[j] + lnb[j];
        hout[(long)b * hstride + j] = __float2bfloat16(h);
    }
}

__global__ __launch_bounds__(256)
void gate_ew(const __hip_bfloat16* __restrict__ g, float* __restrict__ c,
             const float* __restrict__ ret,
             const float* __restrict__ elg, const float* __restrict__ elb,
             const float* __restrict__ lng, const float* __restrict__ lnb,
             __hip_bfloat16* __restrict__ hout, long hstride) {
    gate_ew_body(g, c, ret, elg, elb, lng, lnb, hout, hstride, blockIdx.x);
}

// Dual elementwise: blocks [0,B) run problem A, [B,2B) problem B.
__global__ __launch_bounds__(256)
void gate_ew_dual(const __hip_bfloat16* ga, float* ca, const float* reta,
                  const float* elga, const float* elba,
                  const float* lnga, const float* lnba,
                  __hip_bfloat16* houta, long hstridea,
                  const __hip_bfloat16* gb, float* cb, const float* retb,
                  const float* elgb, const float* elbb,
                  const float* lngb, const float* lnbb,
                  __hip_bfloat16* houtb, long hstrideb) {
    int bid = blockIdx.x;
    bool isB = bid >= B_;
    int b = isB ? bid - B_ : bid;
    const __hip_bfloat16* g = isB ? gb : ga;
    float* c        = isB ? cb : ca;
    const float* ret = isB ? retb : reta;
    const float* elg = isB ? elgb : elga;
    const float* elb = isB ? elbb : elba;
    const float* lng = isB ? lngb : lnga;
    const float* lnb = isB ? lnbb : lnba;
    __hip_bfloat16* hout = isB ? houtb : houta;
    long hstride = isB ? hstrideb : hstridea;
    gate_ew_body(g, c, ret, elg, elb, lng, lnb, hout, hstride, b);
}

// ---------------------------------------------------------------------------
// Attention for the last query only. One wave per (b, head), b chunk-local.
// kv: [KVCHUNK*30, 1024] bf16, cols 0..511 = k, 512..1023 = v.
// ---------------------------------------------------------------------------
__global__ __launch_bounds__(64)
void attn_kernel(const float* __restrict__ q, const __hip_bfloat16* __restrict__ kv,
                 __hip_bfloat16* __restrict__ outv) {
    const int bh = blockIdx.x;
    const int b = bh >> 2, h = bh & 3;
    const int l = threadIdx.x;
    const float scale = 0.0883883476483184f;  // 1/sqrt(128)
    float q0 = q[(long)b * H_ + h * DH_ + l];
    float q1 = q[(long)b * H_ + h * DH_ + 64 + l];
    __shared__ float p[32];
    for (int t = 0; t < TT; ++t) {
        const __hip_bfloat16* kp = kv + ((long)b * TT + t) * 1024 + h * DH_;
        float s = q0 * __bfloat162float(kp[l]) + q1 * __bfloat162float(kp[64 + l]);
        #pragma unroll
        for (int o = 32; o > 0; o >>= 1) s += __shfl_down(s, o, 64);
        if (l == 0) p[t] = s * scale;
    }
    __syncthreads();
    float mx = -1e30f;
    for (int t = 0; t < TT; ++t) mx = fmaxf(mx, p[t]);
    float den = 0.f;
    for (int t = 0; t < TT; ++t) den += __expf(p[t] - mx);
    float a0 = 0.f, a1 = 0.f;
    for (int t = 0; t < TT; ++t) {
        float wt = __expf(p[t] - mx);
        const __hip_bfloat16* vp = kv + ((long)b * TT + t) * 1024 + 512 + h * DH_;
        a0 += wt * __bfloat162float(vp[l]);
        a1 += wt * __bfloat162float(vp[64 + l]);
    }
    float inv = 1.f / den;
    outv[(long)b * H_ + h * DH_ + l] = __float2bfloat16(a0 * inv);
    outv[(long)b * H_ + h * DH_ + 64 + l] = __float2bfloat16(a1 * inv);
}

// ---------------------------------------------------------------------------
// Head: bn2 on latent then out (128->14). One block (128 thr) per batch row.
// ---------------------------------------------------------------------------
__global__ __launch_bounds__(128)
void head_kernel(const float* __restrict__ lat_in,
                 const float* __restrict__ g2, const float* __restrict__ b2,
                 const float* __restrict__ rm2, const float* __restrict__ rv2,
                 const float* __restrict__ ow, const float* __restrict__ ob,
                 float* __restrict__ out) {
    const int b = blockIdx.x, tid = threadIdx.x;
    __shared__ float ls[LAT_];
    float a = lat_in[(long)b * LAT_ + tid];
    ls[tid] = (a - rm2[tid]) * rsqrtf(rv2[tid] + EPSF) * g2[tid] + b2[tid];
    __syncthreads();
    if (tid < OUT_) {
        float acc = ob[tid];
        #pragma unroll 4
        for (int j = 0; j < LAT_; ++j) acc += ls[j] * ow[tid * LAT_ + j];
        out[(long)b * OUT_ + tid] = acc;
    }
}

// ---------------------------------------------------------------------------
extern "C" void kernel_launch(void* const* d_in, const int* in_sizes, int n_in,
                              void* d_out, int out_size, void* d_ws, size_t ws_size,
                              hipStream_t stream) {
    const float* x        = (const float*)d_in[0];
    const float* conv1_w  = (const float*)d_in[1];
    const float* conv1_b  = (const float*)d_in[2];
    const float* bn1_g    = (const float*)d_in[3];
    const float* bn1_b    = (const float*)d_in[4];
    const float* bn1_rm   = (const float*)d_in[5];
    const float* bn1_rv   = (const float*)d_in[6];
    const float* comp_w   = (const float*)d_in[7];
    const float* comp_b   = (const float*)d_in[8];
    const float* proj_w   = (const float*)d_in[9];
    const float* proj_b   = (const float*)d_in[10];
    const float* gates_w  = (const float*)d_in[11];
    const float* gates_b  = (const float*)d_in[12];
    const float* retention= (const float*)d_in[13];
    const float* expln_g  = (const float*)d_in[14];
    const float* expln_b  = (const float*)d_in[15];
    const float* ln_g     = (const float*)d_in[16];
    const float* ln_b     = (const float*)d_in[17];
    const float* attn_in_w  = (const float*)d_in[18];
    const float* attn_in_b  = (const float*)d_in[19];
    const float* attn_out_w = (const float*)d_in[20];
    const float* attn_out_b = (const float*)d_in[21];
    const float* bneck_w  = (const float*)d_in[22];
    const float* bneck_b  = (const float*)d_in[23];
    const float* bn2_g    = (const float*)d_in[24];
    const float* bn2_b    = (const float*)d_in[25];
    const float* bn2_rm   = (const float*)d_in[26];
    const float* bn2_rv   = (const float*)d_in[27];
    const float* out_w    = (const float*)d_in[28];
    const float* out_b    = (const float*)d_in[29];
    float* out = (float*)d_out;

    // ---- compact workspace layout (~218 MiB total) ----
    char* base = (char*)d_ws;
    size_t off = 0;
    auto alloc = [&](size_t nbytes) -> char* {
        char* p = base + off;
        off += (nbytes + 255) & ~(size_t)255;
        return p;
    };
    __hip_bfloat16* seq_bf = (__hip_bfloat16*)alloc((size_t)B_ * TT * H_ * 2);   // 126 MB
    // union: feat (front-end) / 2x bf16 gate buffers (scan) / kv chunk (attn)
    size_t g_bytes    = (size_t)B_ * NGATE_ * 2;                                 // 21 MB
    size_t kv_bytes   = (size_t)KVCHUNK * TT * 1024 * 2;                         // 31.4 MB
    size_t un_bytes   = 2 * g_bytes;                                             // 42 MB (max)
    char* un = alloc(un_bytes);
    __hip_bfloat16* feat_bf = (__hip_bfloat16*)un;
    __hip_bfloat16* gA_bf   = (__hip_bfloat16*)un;                 // layer-1 gates
    __hip_bfloat16* gB_bf   = (__hip_bfloat16*)(un + g_bytes);     // layer-0 gates
    __hip_bfloat16* kv_bf   = (__hip_bfloat16*)un;
    (void)kv_bytes;
    float*          c0    = (float*)alloc((size_t)B_ * H_ * 4);   // c0,c1 contiguous
    float*          c1    = (float*)alloc((size_t)B_ * H_ * 4);
    __hip_bfloat16* h0_bf = (__hip_bfloat16*)alloc((size_t)B_ * H_ * 2);
    float*          q_f   = (float*)alloc((size_t)B_ * H_ * 4);   // reused as fin_bf
    __hip_bfloat16* fin_bf = (__hip_bfloat16*)q_f;
    __hip_bfloat16* av_bf = (__hip_bfloat16*)alloc((size_t)B_ * H_ * 2);
    float*          lat_f = (float*)alloc((size_t)B_ * LAT_ * 4); // 2.1 MB
    __hip_bfloat16* gw_bf = (__hip_bfloat16*)alloc((size_t)L_ * 5 * H_ * 2 * H_ * 2);
    __hip_bfloat16* ai_bf = (__hip_bfloat16*)alloc((size_t)3 * H_ * H_ * 2);
    __hip_bfloat16* ao_bf = (__hip_bfloat16*)alloc((size_t)H_ * H_ * 2);
    __hip_bfloat16* pw_bf = (__hip_bfloat16*)alloc((size_t)H_ * FEATK * 2);
    __hip_bfloat16* bw_bf = (__hip_bfloat16*)alloc((size_t)LAT_ * H_ * 2);
    (void)ws_size; (void)in_sizes; (void)n_in; (void)out_size;

    // ---- weight conversion + state zeroing ----
    cvt_bf16<<<2048, 256, 0, stream>>>(gates_w, gw_bf, (long)L_ * 5 * H_ * 2 * H_);
    cvt_bf16<<<512, 256, 0, stream>>>(attn_in_w, ai_bf, (long)3 * H_ * H_);
    cvt_bf16<<<256, 256, 0, stream>>>(attn_out_w, ao_bf, (long)H_ * H_);
    cvt_bf16<<<64, 256, 0, stream>>>(bneck_w, bw_bf, (long)LAT_ * H_);
    pad_projw<<<(H_ * FEATK + 255) / 256, 256, 0, stream>>>(proj_w, pw_bf);
    zero_f32<<<2048, 256, 0, stream>>>(c0, (long)2 * B_ * H_);   // c0+c1 contiguous

    // ---- front-end: feat, then proj via MFMA GEMM ----
    frontend_kernel<<<B_, 256, 0, stream>>>(x, conv1_w, conv1_b, bn1_g, bn1_b, bn1_rm,
                                            bn1_rv, comp_w, comp_b, feat_bf);
    gemm_bias<1><<<dim3(H_ / 128, (B_ * TT) / 128), 256, 0, stream>>>(
        feat_bf, FEATK, (const __hip_bfloat16*)nullptr, 0, FEATK,
        pw_bf, FEATK, proj_b, (void*)seq_bf, H_, FEATK);

    // ---- recurrent scan (software-pipelined: layer1(t) || layer0(t+1)) ----
    const int WL = 5 * H_ * 2 * H_;  // weight elems per layer
    const dim3 ggrid(NGATE_ / 128, B_ / 128);

    // prologue: layer0 step 0 (h0==0 -> K=512 prefix)
    gemm_bias<1><<<ggrid, 256, 0, stream>>>(
        seq_bf, TT * H_, (const __hip_bfloat16*)nullptr, 0, H_,
        gw_bf, 2 * H_, gates_b, (void*)gB_bf, NGATE_, H_);
    gate_ew<<<B_, 256, 0, stream>>>(gB_bf, c0, retention, expln_g, expln_b,
                                    ln_g, ln_b, h0_bf, H_);

    for (int t = 0; t < TT - 1; ++t) {
        // problem A: layer1(t)  [t=0: h1 prev == 0 -> K=512 prefix]
        // problem B: layer0(t+1)
        gemm_bias_dual_x<1><<<1280, 256, 0, stream>>>(
            h0_bf, H_, (t == 0) ? (const __hip_bfloat16*)nullptr
                                : seq_bf + (size_t)(t - 1) * H_,
            TT * H_, (t == 0) ? H_ : 2 * H_, gw_bf + WL, gates_b + NGATE_, (void*)gA_bf,
            seq_bf + (size_t)(t + 1) * H_, TT * H_, h0_bf, H_, 2 * H_,
            gw_bf, gates_b, (void*)gB_bf,
            H_, 2 * H_, NGATE_);
        gate_ew_dual<<<2 * B_, 256, 0, stream>>>(
            gA_bf, c1, retention + H_, expln_g + H_, expln_b + H_,
            ln_g + H_, ln_b + H_, seq_bf + (size_t)t * H_, TT * H_,
            gB_bf, c0, retention, expln_g, expln_b,
            ln_g, ln_b, h0_bf, H_);
    }
    // epilogue: layer1 step 29
    gemm_bias<1><<<ggrid, 256, 0, stream>>>(
        h0_bf, H_, seq_bf + (size_t)(TT - 2) * H_, TT * H_, H_,
        gw_bf + WL, 2 * H_, gates_b + NGATE_, (void*)gA_bf, NGATE_, 2 * H_);
    gate_ew<<<B_, 256, 0, stream>>>(gA_bf, c1, retention + H_, expln_g + H_,
                                    expln_b + H_, ln_g + H_, ln_b + H_,
                                    seq_bf + (size_t)(TT - 1) * H_, TT * H_);

    // ---- q projection (last timestep only) ----
    gemm_bias<0><<<dim3(H_ / 128, B_ / 128), 256, 0, stream>>>(
        seq_bf + (size_t)29 * H_, TT * H_, (const __hip_bfloat16*)nullptr, 0, H_,
        ai_bf, H_, attn_in_b, (void*)q_f, H_, H_);

    // ---- kv projection + attention, in 8 batch chunks of KVCHUNK rows ----
    for (int bc = 0; bc < B_ / KVCHUNK; ++bc) {
        const __hip_bfloat16* seq_c = seq_bf + (size_t)bc * KVCHUNK * TT * H_;
        gemm_bias<1><<<dim3(1024 / 128, (KVCHUNK * TT) / 128), 256, 0, stream>>>(
            seq_c, H_, (const __hip_bfloat16*)nullptr, 0, H_,
            ai_bf + (size_t)H_ * H_, H_, attn_in_b + H_, (void*)kv_bf, 2 * H_, H_);
        attn_kernel<<<KVCHUNK * NH_, 64, 0, stream>>>(
            q_f + (size_t)bc * KVCHUNK * H_, kv_bf, av_bf + (size_t)bc * KVCHUNK * H_);
    }

    // ---- attn_out projection -> bf16 fin (aliases q_f; q fully consumed) ----
    gemm_bias<1><<<dim3(H_ / 128, B_ / 128), 256, 0, stream>>>(
        av_bf, H_, (const __hip_bfloat16*)nullptr, 0, H_,
        ao_bf, H_, attn_out_b, (void*)fin_bf, H_, H_);

    // ---- bneck via MFMA GEMM -> latent f32, then bn2+head ----
    gemm_bias<0><<<dim3(LAT_ / 128, B_ / 128), 256, 0, stream>>>(
        fin_bf, H_, (const __hip_bfloat16*)nullptr, 0, H_,
        bw_bf, H_, bneck_b, (void*)lat_f, LAT_, H_);
    head_kernel<<<B_, 128, 0, stream>>>(lat_f, bn2_g, bn2_b, bn2_rm, bn2_rv,
                                        out_w, out_b, out);
}

// Round 8
// 3203.138 us; speedup vs baseline: 1.2509x; 1.0463x over previous
//
#include <hip/hip_runtime.h>
#include <hip/hip_bf16.h>

// Problem constants
#define B_   4096
#define T_   60
#define TT   30          // pooled sequence length
#define H_   512
#define L_   2
#define NH_  4
#define DH_  128
#define LAT_ 128
#define OUT_ 14
#define NGATE_ (5*H_)    // 2560
#define EPSF 1e-5f
#define KVCHUNK 512      // batch rows per kv chunk (8 chunks)
#define FEATK 64         // feat padded to 64 (GEMM K granularity)

typedef __attribute__((ext_vector_type(8))) short bf16x8;
typedef __attribute__((ext_vector_type(4))) float f32x4;

__device__ __forceinline__ float sigmoidf_(float x) { return 1.0f / (1.0f + __expf(-x)); }

__device__ __forceinline__ void async_load16(const void* g, void* l) {
    __builtin_amdgcn_global_load_lds((const __attribute__((address_space(1))) void*)g,
                                     (__attribute__((address_space(3))) void*)l, 16, 0, 0);
}

// ---------------------------------------------------------------------------
// Utility kernels
// ---------------------------------------------------------------------------
__global__ __launch_bounds__(256) void cvt_bf16(const float* __restrict__ in,
                                                __hip_bfloat16* __restrict__ out, long n) {
    long i = (long)blockIdx.x * blockDim.x + threadIdx.x;
    long stride = (long)gridDim.x * blockDim.x;
    for (; i < n; i += stride) out[i] = __float2bfloat16(in[i]);
}

__global__ __launch_bounds__(256) void zero_f32(float* __restrict__ p, long n) {
    long i = (long)blockIdx.x * blockDim.x + threadIdx.x;
    long stride = (long)gridDim.x * blockDim.x;
    for (; i < n; i += stride) p[i] = 0.0f;
}

// proj_w [512,44] f32 -> padded [512,64] bf16 (cols 44..63 zero)
__global__ __launch_bounds__(256) void pad_projw(const float* __restrict__ pw,
                                                 __hip_bfloat16* __restrict__ out) {
    int i = blockIdx.x * 256 + threadIdx.x;      // 512*64 = 32768
    if (i >= H_ * FEATK) return;
    int r = i >> 6, c = i & 63;
    out[i] = __float2bfloat16(c < 44 ? pw[r * 44 + c] : 0.f);
}

// ---------------------------------------------------------------------------
// Front-end: conv1d(9->24,k3,p1)+relu+bn -> maxpool2 -> concat comp(8->20 relu)
// Writes feat [B*TT, 64] bf16 (cols 44..63 zero). Proj happens via MFMA GEMM.
// ---------------------------------------------------------------------------
__global__ __launch_bounds__(256)
void frontend_kernel(const float* __restrict__ x,
                     const float* __restrict__ cw, const float* __restrict__ cb,
                     const float* __restrict__ bg, const float* __restrict__ bb,
                     const float* __restrict__ brm, const float* __restrict__ brv,
                     const float* __restrict__ compw, const float* __restrict__ compb,
                     __hip_bfloat16* __restrict__ feat_out) {
    const int b = blockIdx.x, tid = threadIdx.x;
    __shared__ float xs[T_ * 17];        // 4080 B
    __shared__ float ybuf[24][T_];       // 5760 B
    __shared__ float feat[TT][44];       // 5280 B

    for (int i = tid; i < T_ * 17; i += 256) xs[i] = x[(long)b * T_ * 17 + i];
    __syncthreads();

    // conv + relu + bn1
    for (int i = tid; i < 24 * T_; i += 256) {
        int oc = i / T_, t = i % T_;
        float acc = cb[oc];
        #pragma unroll
        for (int kk = 0; kk < 3; ++kk) {
            int tt = t + kk - 1;
            if (tt >= 0 && tt < T_) {
                #pragma unroll
                for (int ic = 0; ic < 9; ++ic)
                    acc += xs[tt * 17 + ic] * cw[(oc * 9 + ic) * 3 + kk];
            }
        }
        acc = fmaxf(acc, 0.f);
        acc = (acc - brm[oc]) * rsqrtf(brv[oc] + EPSF) * bg[oc] + bb[oc];
        ybuf[oc][t] = acc;
    }
    __syncthreads();

    // maxpool(2) -> feat[:, :24]
    for (int i = tid; i < TT * 24; i += 256) {
        int u = i / 24, oc = i % 24;
        feat[u][oc] = fmaxf(ybuf[oc][2 * u], ybuf[oc][2 * u + 1]);
    }
    // comp: relu(x[:, :30, 9:17] @ comp_w.T + b) -> feat[:, 24:44]
    for (int i = tid; i < TT * 20; i += 256) {
        int u = i / 20, oc = i % 20;
        float acc = compb[oc];
        #pragma unroll
        for (int j = 0; j < 8; ++j) acc += xs[u * 17 + 9 + j] * compw[oc * 8 + j];
        feat[u][24 + oc] = fmaxf(acc, 0.f);
    }
    __syncthreads();

    // write padded bf16 feat rows
    for (int i = tid; i < TT * FEATK; i += 256) {
        int u = i >> 6, c = i & 63;
        float v = (c < 44) ? feat[u][c] : 0.f;
        feat_out[((long)b * TT + u) * FEATK + c] = __float2bfloat16(v);
    }
}

// ---------------------------------------------------------------------------
// bf16 MFMA GEMM core: C[m,n] = sum_k A[m,k] * W[n,k] + bias[n]
// A split along K at `ksplit` between A0 (stride lda0) and A1 (stride lda1).
// W has row stride ldw (>= K). 128x128 tile, BK=64, global_load_lds staging.
//
// LDS bank-conflict fix (R5, verified: SQ_LDS_BANK_CONFLICT 1.57e7 -> 0):
// LDS slot (row, c) holds global K-chunk c ^ (row&7); permutation applied on
// the global SOURCE address. Plain epilogue stores (R7: NT stores of
// scattered 2B caused 1.35x write amplification — L2 IS the write combiner).
// ---------------------------------------------------------------------------
template <int WRITE_BF16>
__device__ __forceinline__
void gemm_core(const __hip_bfloat16* __restrict__ A0, int lda0,
               const __hip_bfloat16* __restrict__ A1, int lda1, int ksplit,
               const __hip_bfloat16* __restrict__ W, int ldw,
               const float* __restrict__ bias,
               void* __restrict__ Cout, int ldc, int K, int bx, int by) {
    __shared__ __hip_bfloat16 As[128 * 64];
    __shared__ __hip_bfloat16 Bs[128 * 64];
    const int tid = threadIdx.x;
    const int wave = tid >> 6, lane = tid & 63;
    const long m0 = (long)by * 128;
    const long n0 = (long)bx * 128;

    f32x4 acc[4][4] = {};

    for (int k0 = 0; k0 < K; k0 += 64) {
        __syncthreads();
        #pragma unroll
        for (int it = 0; it < 4; ++it) {
            int id = it * 256 + tid;          // 0..1023 -> 16 B each
            int row = id >> 3;                // 0..127
            int kc = ((id & 7) ^ (row & 7)) << 3;   // swizzled source chunk
            int gk = k0 + kc;
            const __hip_bfloat16* srcA;
            if (gk < ksplit) srcA = A0 + (m0 + row) * (long)lda0 + gk;
            else             srcA = A1 + (m0 + row) * (long)lda1 + (gk - ksplit);
            async_load16(srcA, &As[id * 8]);
            const __hip_bfloat16* srcB = W + (n0 + row) * (long)ldw + gk;
            async_load16(srcB, &Bs[id * 8]);
        }
        __syncthreads();
        #pragma unroll
        for (int ks = 0; ks < 2; ++ks) {
            const int kb = ((ks * 4 + (lane >> 4)) ^ (lane & 7)) << 3;
            const int ar = (wave >> 1) * 64 + (lane & 15);
            const int br = (wave & 1) * 64 + (lane & 15);
            bf16x8 afr[4], bfr[4];
            #pragma unroll
            for (int i = 0; i < 4; ++i) afr[i] = *(const bf16x8*)&As[(ar + i * 16) * 64 + kb];
            #pragma unroll
            for (int i = 0; i < 4; ++i) bfr[i] = *(const bf16x8*)&Bs[(br + i * 16) * 64 + kb];
            #pragma unroll
            for (int mi = 0; mi < 4; ++mi)
                #pragma unroll
                for (int ni = 0; ni < 4; ++ni)
                    acc[mi][ni] = __builtin_amdgcn_mfma_f32_16x16x32_bf16(afr[mi], bfr[ni], acc[mi][ni], 0, 0, 0);
        }
    }

    // epilogue: C/D layout col=lane&15, row=(lane>>4)*4+r
    const int cr = (lane >> 4) * 4;
    const int ccol = lane & 15;
    #pragma unroll
    for (int ni = 0; ni < 4; ++ni) {
        long col = n0 + (wave & 1) * 64 + ni * 16 + ccol;
        float bv = bias ? bias[col] : 0.f;
        #pragma unroll
        for (int mi = 0; mi < 4; ++mi) {
            long rowb = m0 + (wave >> 1) * 64 + mi * 16 + cr;
            #pragma unroll
            for (int r = 0; r < 4; ++r) {
                float v = acc[mi][ni][r] + bv;
                if (WRITE_BF16)
                    ((__hip_bfloat16*)Cout)[(rowb + r) * (long)ldc + col] = __float2bfloat16(v);
                else
                    ((float*)Cout)[(rowb + r) * (long)ldc + col] = v;
            }
        }
    }
}

template <int WRITE_BF16>
__global__ __launch_bounds__(256)
void gemm_bias(const __hip_bfloat16* __restrict__ A0, int lda0,
               const __hip_bfloat16* __restrict__ A1, int lda1, int ksplit,
               const __hip_bfloat16* __restrict__ W, int ldw,
               const float* __restrict__ bias,
               void* __restrict__ Cout, int ldc, int K) {
    gemm_core<WRITE_BF16>(A0, lda0, A1, lda1, ksplit, W, ldw, bias, Cout, ldc, K,
                          blockIdx.x, blockIdx.y);
}

// ---------------------------------------------------------------------------
// Dual-problem gate GEMM with 2D XCD partition (R8).
// R7 post-mortem: col-only pinning made every XCD read ALL of A (8x16.8 =
// 134 MB fill, FETCH 120 MB). Balanced z-separated partition: each XCD gets
// 16 m-tiles x 10 colz-tiles OF ONE PROBLEM:
//   per-XCD fill = A 16/32 x 8.4 MB + W 10 x 256 KB = 6.8 MB -> 54 MB total.
// Decode (id%8 -> XCD round-robin heuristic; correctness never depends on it):
//   xcd = id&7; mhalf = xcd>>2; czg = xcd&3; rest = id>>3 (0..159)
//   m = mhalf*16 + (rest&15); colz = czg*10 + (rest>>4); col=colz%20; z=colz/20
// czg groups align with z (czg 0,1 -> z=0; czg 2,3 -> z=1).
// ---------------------------------------------------------------------------
template <int WRITE_BF16>
__global__ __launch_bounds__(256)
void gemm_bias_dual_x(const __hip_bfloat16* A0a, int lda0a, const __hip_bfloat16* A1a,
                      int lda1a, int Ka, const __hip_bfloat16* Wa,
                      const float* biasa, void* Ca,
                      const __hip_bfloat16* A0b, int lda0b, const __hip_bfloat16* A1b,
                      int lda1b, int Kb, const __hip_bfloat16* Wb,
                      const float* biasb, void* Cb,
                      int ksplit, int ldw, int ldc) {
    const int id = blockIdx.x;
    const int xcd = id & 7;
    const int mhalf = xcd >> 2;        // 0..1
    const int czg = xcd & 3;           // 0..3
    const int rest = id >> 3;          // 0..159
    const int m = mhalf * 16 + (rest & 15);
    const int colz = czg * 10 + (rest >> 4);   // 0..39
    const int col = colz % 20;
    const int z = colz / 20;
    const __hip_bfloat16* A0 = z ? A0b : A0a;
    const __hip_bfloat16* A1 = z ? A1b : A1a;
    const __hip_bfloat16* W  = z ? Wb  : Wa;
    const float* bias        = z ? biasb : biasa;
    void* Cout               = z ? Cb : Ca;
    int lda0 = z ? lda0b : lda0a;
    int lda1 = z ? lda1b : lda1a;
    int K    = z ? Kb : Ka;
    gemm_core<WRITE_BF16>(A0, lda0, A1, lda1, ksplit, W, ldw, bias, Cout, ldc, K,
                          col, m);
}

// ---------------------------------------------------------------------------
// Gate elementwise + the two LayerNorms. One block (256 thr) per batch row.
// g: [B, 2560] bf16 (f,i,o,cc,m blocks of 512). c: [B,512] f32 (updated).
// ---------------------------------------------------------------------------
__device__ __forceinline__ void block_reduce2(float& a, float& b, float* red) {
    #pragma unroll
    for (int off = 32; off > 0; off >>= 1) {
        a += __shfl_down(a, off, 64);
        b += __shfl_down(b, off, 64);
    }
    int lane = threadIdx.x & 63, w = threadIdx.x >> 6;
    if (lane == 0) { red[w] = a; red[8 + w] = b; }
    __syncthreads();
    a = red[0] + red[1] + red[2] + red[3];
    b = red[8] + red[9] + red[10] + red[11];
    __syncthreads();
}

__device__ __forceinline__
void gate_ew_body(const __hip_bfloat16* __restrict__ g, float* __restrict__ c,
                  const float* __restrict__ ret,
                  const float* __restrict__ elg, const float* __restrict__ elb,
                  const float* __restrict__ lng, const float* __restrict__ lnb,
                  __hip_bfloat16* __restrict__ hout, long hstride, int b) {
    const int tid = threadIdx.x;
    const __hip_bfloat16* gr = g + (long)b * NGATE_;
    __shared__ float red[16];

    float o_[2], cn_[2];
    float s = 0.f, s2 = 0.f;
    #pragma unroll
    for (int u = 0; u < 2; ++u) {
        int j = tid + u * 256;
        float fg = __bfloat162float(gr[j]);
        float ig = __bfloat162float(gr[512 + j]);
        float og = __bfloat162float(gr[1024 + j]);
        float cg = __bfloat162float(gr[1536 + j]);
        float mg = __bfloat162float(gr[2048 + j]);
        float f = sigmoidf_(fg), i = sigmoidf_(ig), o = sigmoidf_(og);
        float cc = tanhf(cg), m = sigmoidf_(mg);
        float cold = c[(long)b * H_ + j];
        float r = ret[j];
        float cn = f * cold + i * cc;
        cn = cn * r + (1.f - r) * cold;
        cn = m * cn + (1.f - m) * cold;
        c[(long)b * H_ + j] = cn;
        o_[u] = o; cn_[u] = cn;
        s += o; s2 += o * o;
    }
    block_reduce2(s, s2, red);
    float mean = s * (1.f / H_);
    float var = s2 * (1.f / H_) - mean * mean;
    float rstd = rsqrtf(var + EPSF);

    float val[2];
    float s3 = 0.f, s4 = 0.f;
    #pragma unroll
    for (int u = 0; u < 2; ++u) {
        int j = tid + u * 256;
        float on = (o_[u] - mean) * rstd * elg[j] + elb[j];
        float oe = sigmoidf_(on);
        float v = oe * tanhf(cn_[u]);
        val[u] = v; s3 += v; s4 += v * v;
    }
    block_reduce2(s3, s4, red);
    float mean2 = s3 * (1.f / H_);
    float var2 = s4 * (1.f / H_) - mean2 * mean2;
    float rstd2 = rsqrtf(var2 + EPSF);
    #pragma unroll
    for (int u = 0; u < 2; ++u) {
        int j = tid + u * 256;
        float h = (val[u] - mean2) * rstd2 * lng[j] + lnb[j];
        hout[(long)b * hstride + j] = __float2bfloat16(h);
    }
}

__global__ __launch_bounds__(256)
void gate_ew(const __hip_bfloat16* __restrict__ g, float* __restrict__ c,
             const float* __restrict__ ret,
             const float* __restrict__ elg, const float* __restrict__ elb,
             const float* __restrict__ lng, const float* __restrict__ lnb,
             __hip_bfloat16* __restrict__ hout, long hstride) {
    gate_ew_body(g, c, ret, elg, elb, lng, lnb, hout, hstride, blockIdx.x);
}

// Dual elementwise: blocks [0,B) run problem A, [B,2B) problem B.
__global__ __launch_bounds__(256)
void gate_ew_dual(const __hip_bfloat16* ga, float* ca, const float* reta,
                  const float* elga, const float* elba,
                  const float* lnga, const float* lnba,
                  __hip_bfloat16* houta, long hstridea,
                  const __hip_bfloat16* gb, float* cb, const float* retb,
                  const float* elgb, const float* elbb,
                  const float* lngb, const float* lnbb,
                  __hip_bfloat16* houtb, long hstrideb) {
    int bid = blockIdx.x;
    bool isB = bid >= B_;
    int b = isB ? bid - B_ : bid;
    const __hip_bfloat16* g = isB ? gb : ga;
    float* c        = isB ? cb : ca;
    const float* ret = isB ? retb : reta;
    const float* elg = isB ? elgb : elga;
    const float* elb = isB ? elbb : elba;
    const float* lng = isB ? lngb : lnga;
    const float* lnb = isB ? lnbb : lnba;
    __hip_bfloat16* hout = isB ? houtb : houta;
    long hstride = isB ? hstrideb : hstridea;
    gate_ew_body(g, c, ret, elg, elb, lng, lnb, hout, hstride, b);
}

// ---------------------------------------------------------------------------
// Attention for the last query only. One wave per (b, head), b chunk-local.
// kv: [KVCHUNK*30, 1024] bf16, cols 0..511 = k, 512..1023 = v.
// ---------------------------------------------------------------------------
__global__ __launch_bounds__(64)
void attn_kernel(const float* __restrict__ q, const __hip_bfloat16* __restrict__ kv,
                 __hip_bfloat16* __restrict__ outv) {
    const int bh = blockIdx.x;
    const int b = bh >> 2, h = bh & 3;
    const int l = threadIdx.x;
    const float scale = 0.0883883476483184f;  // 1/sqrt(128)
    float q0 = q[(long)b * H_ + h * DH_ + l];
    float q1 = q[(long)b * H_ + h * DH_ + 64 + l];
    __shared__ float p[32];
    for (int t = 0; t < TT; ++t) {
        const __hip_bfloat16* kp = kv + ((long)b * TT + t) * 1024 + h * DH_;
        float s = q0 * __bfloat162float(kp[l]) + q1 * __bfloat162float(kp[64 + l]);
        #pragma unroll
        for (int o = 32; o > 0; o >>= 1) s += __shfl_down(s, o, 64);
        if (l == 0) p[t] = s * scale;
    }
    __syncthreads();
    float mx = -1e30f;
    for (int t = 0; t < TT; ++t) mx = fmaxf(mx, p[t]);
    float den = 0.f;
    for (int t = 0; t < TT; ++t) den += __expf(p[t] - mx);
    float a0 = 0.f, a1 = 0.f;
    for (int t = 0; t < TT; ++t) {
        float wt = __expf(p[t] - mx);
        const __hip_bfloat16* vp = kv + ((long)b * TT + t) * 1024 + 512 + h * DH_;
        a0 += wt * __bfloat162float(vp[l]);
        a1 += wt * __bfloat162float(vp[64 + l]);
    }
    float inv = 1.f / den;
    outv[(long)b * H_ + h * DH_ + l] = __float2bfloat16(a0 * inv);
    outv[(long)b * H_ + h * DH_ + 64 + l] = __float2bfloat16(a1 * inv);
}

// ---------------------------------------------------------------------------
// Head: bn2 on latent then out (128->14). One block (128 thr) per batch row.
// ---------------------------------------------------------------------------
__global__ __launch_bounds__(128)
void head_kernel(const float* __restrict__ lat_in,
                 const float* __restrict__ g2, const float* __restrict__ b2,
                 const float* __restrict__ rm2, const float* __restrict__ rv2,
                 const float* __restrict__ ow, const float* __restrict__ ob,
                 float* __restrict__ out) {
    const int b = blockIdx.x, tid = threadIdx.x;
    __shared__ float ls[LAT_];
    float a = lat_in[(long)b * LAT_ + tid];
    ls[tid] = (a - rm2[tid]) * rsqrtf(rv2[tid] + EPSF) * g2[tid] + b2[tid];
    __syncthreads();
    if (tid < OUT_) {
        float acc = ob[tid];
        #pragma unroll 4
        for (int j = 0; j < LAT_; ++j) acc += ls[j] * ow[tid * LAT_ + j];
        out[(long)b * OUT_ + tid] = acc;
    }
}

// ---------------------------------------------------------------------------
extern "C" void kernel_launch(void* const* d_in, const int* in_sizes, int n_in,
                              void* d_out, int out_size, void* d_ws, size_t ws_size,
                              hipStream_t stream) {
    const float* x        = (const float*)d_in[0];
    const float* conv1_w  = (const float*)d_in[1];
    const float* conv1_b  = (const float*)d_in[2];
    const float* bn1_g    = (const float*)d_in[3];
    const float* bn1_b    = (const float*)d_in[4];
    const float* bn1_rm   = (const float*)d_in[5];
    const float* bn1_rv   = (const float*)d_in[6];
    const float* comp_w   = (const float*)d_in[7];
    const float* comp_b   = (const float*)d_in[8];
    const float* proj_w   = (const float*)d_in[9];
    const float* proj_b   = (const float*)d_in[10];
    const float* gates_w  = (const float*)d_in[11];
    const float* gates_b  = (const float*)d_in[12];
    const float* retention= (const float*)d_in[13];
    const float* expln_g  = (const float*)d_in[14];
    const float* expln_b  = (const float*)d_in[15];
    const float* ln_g     = (const float*)d_in[16];
    const float* ln_b     = (const float*)d_in[17];
    const float* attn_in_w  = (const float*)d_in[18];
    const float* attn_in_b  = (const float*)d_in[19];
    const float* attn_out_w = (const float*)d_in[20];
    const float* attn_out_b = (const float*)d_in[21];
    const float* bneck_w  = (const float*)d_in[22];
    const float* bneck_b  = (const float*)d_in[23];
    const float* bn2_g    = (const float*)d_in[24];
    const float* bn2_b    = (const float*)d_in[25];
    const float* bn2_rm   = (const float*)d_in[26];
    const float* bn2_rv   = (const float*)d_in[27];
    const float* out_w    = (const float*)d_in[28];
    const float* out_b    = (const float*)d_in[29];
    float* out = (float*)d_out;

    // ---- compact workspace layout (~218 MiB total) ----
    char* base = (char*)d_ws;
    size_t off = 0;
    auto alloc = [&](size_t nbytes) -> char* {
        char* p = base + off;
        off += (nbytes + 255) & ~(size_t)255;
        return p;
    };
    __hip_bfloat16* seq_bf = (__hip_bfloat16*)alloc((size_t)B_ * TT * H_ * 2);   // 126 MB
    // union: feat (front-end) / 2x bf16 gate buffers (scan) / kv chunk (attn)
    size_t g_bytes    = (size_t)B_ * NGATE_ * 2;                                 // 21 MB
    size_t kv_bytes   = (size_t)KVCHUNK * TT * 1024 * 2;                         // 31.4 MB
    size_t un_bytes   = 2 * g_bytes;                                             // 42 MB (max)
    char* un = alloc(un_bytes);
    __hip_bfloat16* feat_bf = (__hip_bfloat16*)un;
    __hip_bfloat16* gA_bf   = (__hip_bfloat16*)un;                 // layer-1 gates
    __hip_bfloat16* gB_bf   = (__hip_bfloat16*)(un + g_bytes);     // layer-0 gates
    __hip_bfloat16* kv_bf   = (__hip_bfloat16*)un;
    (void)kv_bytes;
    float*          c0    = (float*)alloc((size_t)B_ * H_ * 4);   // c0,c1 contiguous
    float*          c1    = (float*)alloc((size_t)B_ * H_ * 4);
    __hip_bfloat16* h0_bf = (__hip_bfloat16*)alloc((size_t)B_ * H_ * 2);
    float*          q_f   = (float*)alloc((size_t)B_ * H_ * 4);   // reused as fin_bf
    __hip_bfloat16* fin_bf = (__hip_bfloat16*)q_f;
    __hip_bfloat16* av_bf = (__hip_bfloat16*)alloc((size_t)B_ * H_ * 2);
    float*          lat_f = (float*)alloc((size_t)B_ * LAT_ * 4); // 2.1 MB
    __hip_bfloat16* gw_bf = (__hip_bfloat16*)alloc((size_t)L_ * 5 * H_ * 2 * H_ * 2);
    __hip_bfloat16* ai_bf = (__hip_bfloat16*)alloc((size_t)3 * H_ * H_ * 2);
    __hip_bfloat16* ao_bf = (__hip_bfloat16*)alloc((size_t)H_ * H_ * 2);
    __hip_bfloat16* pw_bf = (__hip_bfloat16*)alloc((size_t)H_ * FEATK * 2);
    __hip_bfloat16* bw_bf = (__hip_bfloat16*)alloc((size_t)LAT_ * H_ * 2);
    (void)ws_size; (void)in_sizes; (void)n_in; (void)out_size;

    // ---- weight conversion + state zeroing ----
    cvt_bf16<<<2048, 256, 0, stream>>>(gates_w, gw_bf, (long)L_ * 5 * H_ * 2 * H_);
    cvt_bf16<<<512, 256, 0, stream>>>(attn_in_w, ai_bf, (long)3 * H_ * H_);
    cvt_bf16<<<256, 256, 0, stream>>>(attn_out_w, ao_bf, (long)H_ * H_);
    cvt_bf16<<<64, 256, 0, stream>>>(bneck_w, bw_bf, (long)LAT_ * H_);
    pad_projw<<<(H_ * FEATK + 255) / 256, 256, 0, stream>>>(proj_w, pw_bf);
    zero_f32<<<2048, 256, 0, stream>>>(c0, (long)2 * B_ * H_);   // c0+c1 contiguous

    // ---- front-end: feat, then proj via MFMA GEMM ----
    frontend_kernel<<<B_, 256, 0, stream>>>(x, conv1_w, conv1_b, bn1_g, bn1_b, bn1_rm,
                                            bn1_rv, comp_w, comp_b, feat_bf);
    gemm_bias<1><<<dim3(H_ / 128, (B_ * TT) / 128), 256, 0, stream>>>(
        feat_bf, FEATK, (const __hip_bfloat16*)nullptr, 0, FEATK,
        pw_bf, FEATK, proj_b, (void*)seq_bf, H_, FEATK);

    // ---- recurrent scan (software-pipelined: layer1(t) || layer0(t+1)) ----
    const int WL = 5 * H_ * 2 * H_;  // weight elems per layer
    const dim3 ggrid(NGATE_ / 128, B_ / 128);

    // prologue: layer0 step 0 (h0==0 -> K=512 prefix)
    gemm_bias<1><<<ggrid, 256, 0, stream>>>(
        seq_bf, TT * H_, (const __hip_bfloat16*)nullptr, 0, H_,
        gw_bf, 2 * H_, gates_b, (void*)gB_bf, NGATE_, H_);
    gate_ew<<<B_, 256, 0, stream>>>(gB_bf, c0, retention, expln_g, expln_b,
                                    ln_g, ln_b, h0_bf, H_);

    for (int t = 0; t < TT - 1; ++t) {
        // problem A: layer1(t)  [t=0: h1 prev == 0 -> K=512 prefix]
        // problem B: layer0(t+1)
        gemm_bias_dual_x<1><<<1280, 256, 0, stream>>>(
            h0_bf, H_, (t == 0) ? (const __hip_bfloat16*)nullptr
                                : seq_bf + (size_t)(t - 1) * H_,
            TT * H_, (t == 0) ? H_ : 2 * H_, gw_bf + WL, gates_b + NGATE_, (void*)gA_bf,
            seq_bf + (size_t)(t + 1) * H_, TT * H_, h0_bf, H_, 2 * H_,
            gw_bf, gates_b, (void*)gB_bf,
            H_, 2 * H_, NGATE_);
        gate_ew_dual<<<2 * B_, 256, 0, stream>>>(
            gA_bf, c1, retention + H_, expln_g + H_, expln_b + H_,
            ln_g + H_, ln_b + H_, seq_bf + (size_t)t * H_, TT * H_,
            gB_bf, c0, retention, expln_g, expln_b,
            ln_g, ln_b, h0_bf, H_);
    }
    // epilogue: layer1 step 29
    gemm_bias<1><<<ggrid, 256, 0, stream>>>(
        h0_bf, H_, seq_bf + (size_t)(TT - 2) * H_, TT * H_, H_,
        gw_bf + WL, 2 * H_, gates_b + NGATE_, (void*)gA_bf, NGATE_, 2 * H_);
    gate_ew<<<B_, 256, 0, stream>>>(gA_bf, c1, retention + H_, expln_g + H_,
                                    expln_b + H_, ln_g + H_, ln_b + H_,
                                    seq_bf + (size_t)(TT - 1) * H_, TT * H_);

    // ---- q projection (last timestep only) ----
    gemm_bias<0><<<dim3(H_ / 128, B_ / 128), 256, 0, stream>>>(
        seq_bf + (size_t)29 * H_, TT * H_, (const __hip_bfloat16*)nullptr, 0, H_,
        ai_bf, H_, attn_in_b, (void*)q_f, H_, H_);

    // ---- kv projection + attention, in 8 batch chunks of KVCHUNK rows ----
    for (int bc = 0; bc < B_ / KVCHUNK; ++bc) {
        const __hip_bfloat16* seq_c = seq_bf + (size_t)bc * KVCHUNK * TT * H_;
        gemm_bias<1><<<dim3(1024 / 128, (KVCHUNK * TT) / 128), 256, 0, stream>>>(
            seq_c, H_, (const __hip_bfloat16*)nullptr, 0, H_,
            ai_bf + (size_t)H_ * H_, H_, attn_in_b + H_, (void*)kv_bf, 2 * H_, H_);
        attn_kernel<<<KVCHUNK * NH_, 64, 0, stream>>>(
            q_f + (size_t)bc * KVCHUNK * H_, kv_bf, av_bf + (size_t)bc * KVCHUNK * H_);
    }

    // ---- attn_out projection -> bf16 fin (aliases q_f; q fully consumed) ----
    gemm_bias<1><<<dim3(H_ / 128, B_ / 128), 256, 0, stream>>>(
        av_bf, H_, (const __hip_bfloat16*)nullptr, 0, H_,
        ao_bf, H_, attn_out_b, (void*)fin_bf, H_, H_);

    // ---- bneck via MFMA GEMM -> latent f32, then bn2+head ----
    gemm_bias<0><<<dim3(LAT_ / 128, B_ / 128), 256, 0, stream>>>(
        fin_bf, H_, (const __hip_bfloat16*)nullptr, 0, H_,
        bw_bf, H_, bneck_b, (void*)lat_f, LAT_, H_);
    head_kernel<<<B_, 128, 0, stream>>>(lat_f, bn2_g, bn2_b, bn2_rm, bn2_rv,
                                        out_w, out_b, out);
}

// Round 9
// 2882.807 us; speedup vs baseline: 1.3899x; 1.1111x over previous
//
#include <hip/hip_runtime.h>
#include <hip/hip_bf16.h>

// Problem constants
#define B_   4096
#define T_   60
#define TT   30          // pooled sequence length
#define H_   512
#define L_   2
#define NH_  4
#define DH_  128
#define LAT_ 128
#define OUT_ 14
#define NGATE_ (5*H_)    // 2560
#define EPSF 1e-5f
#define FEATK 64         // feat padded to 64 (GEMM K granularity)

typedef __attribute__((ext_vector_type(8))) short bf16x8;
typedef __attribute__((ext_vector_type(4))) float f32x4;

__device__ __forceinline__ float sigmoidf_(float x) { return 1.0f / (1.0f + __expf(-x)); }
__device__ __forceinline__ float bf2f(short s) {
    return __uint_as_float(((unsigned)(unsigned short)s) << 16);
}

__device__ __forceinline__ void async_load16(const void* g, void* l) {
    __builtin_amdgcn_global_load_lds((const __attribute__((address_space(1))) void*)g,
                                     (__attribute__((address_space(3))) void*)l, 16, 0, 0);
}

// ---------------------------------------------------------------------------
// Utility kernels
// ---------------------------------------------------------------------------
__global__ __launch_bounds__(256) void cvt_bf16(const float* __restrict__ in,
                                                __hip_bfloat16* __restrict__ out, long n) {
    long i = (long)blockIdx.x * blockDim.x + threadIdx.x;
    long stride = (long)gridDim.x * blockDim.x;
    for (; i < n; i += stride) out[i] = __float2bfloat16(in[i]);
}

__global__ __launch_bounds__(256) void zero_f32(float* __restrict__ p, long n) {
    long i = (long)blockIdx.x * blockDim.x + threadIdx.x;
    long stride = (long)gridDim.x * blockDim.x;
    for (; i < n; i += stride) p[i] = 0.0f;
}

// proj_w [512,44] f32 -> padded [512,64] bf16 (cols 44..63 zero)
__global__ __launch_bounds__(256) void pad_projw(const float* __restrict__ pw,
                                                 __hip_bfloat16* __restrict__ out) {
    int i = blockIdx.x * 256 + threadIdx.x;
    if (i >= H_ * FEATK) return;
    int r = i >> 6, c = i & 63;
    out[i] = __float2bfloat16(c < 44 ? pw[r * 44 + c] : 0.f);
}

// Block-diagonal W_k^T: wkd[n=h*512+i, k] = W_k[k,i] if k in h's 128-slice.
// U[b,n] = sum_k q[b,k] * wkd[n,k]  ->  score(b,h,t) = U(b,h,:).seq(b,t,:)
__global__ __launch_bounds__(256)
void build_wkd(const float* __restrict__ aiw, __hip_bfloat16* __restrict__ wkd) {
    int i = blockIdx.x * 256 + threadIdx.x;          // 2048*512
    if (i >= 2048 * 512) return;
    int n = i >> 9, k = i & 511;
    float v = ((k >> 7) == (n >> 9)) ? aiw[(H_ + k) * H_ + (n & 511)] : 0.f;
    wkd[i] = __float2bfloat16(v);
}

// Block-diagonal W_v: wvd[n, k=h*512+i] = W_v[n,i] if h == n>>7.
// o[b,n] = sum_k sbar[b,k] * wvd[n,k] + bv[n]
__global__ __launch_bounds__(256)
void build_wvd(const float* __restrict__ aiw, __hip_bfloat16* __restrict__ wvd) {
    int i = blockIdx.x * 256 + threadIdx.x;          // 512*2048
    if (i >= 512 * 2048) return;
    int n = i >> 11, k = i & 2047;
    float v = ((k >> 9) == (n >> 7)) ? aiw[(2 * H_ + n) * H_ + (k & 511)] : 0.f;
    wvd[i] = __float2bfloat16(v);
}

// ---------------------------------------------------------------------------
// Front-end: conv1d(9->24,k3,p1)+relu+bn -> maxpool2 -> concat comp(8->20 relu)
// ---------------------------------------------------------------------------
__global__ __launch_bounds__(256)
void frontend_kernel(const float* __restrict__ x,
                     const float* __restrict__ cw, const float* __restrict__ cb,
                     const float* __restrict__ bg, const float* __restrict__ bb,
                     const float* __restrict__ brm, const float* __restrict__ brv,
                     const float* __restrict__ compw, const float* __restrict__ compb,
                     __hip_bfloat16* __restrict__ feat_out) {
    const int b = blockIdx.x, tid = threadIdx.x;
    __shared__ float xs[T_ * 17];
    __shared__ float ybuf[24][T_];
    __shared__ float feat[TT][44];

    for (int i = tid; i < T_ * 17; i += 256) xs[i] = x[(long)b * T_ * 17 + i];
    __syncthreads();

    for (int i = tid; i < 24 * T_; i += 256) {
        int oc = i / T_, t = i % T_;
        float acc = cb[oc];
        #pragma unroll
        for (int kk = 0; kk < 3; ++kk) {
            int tt = t + kk - 1;
            if (tt >= 0 && tt < T_) {
                #pragma unroll
                for (int ic = 0; ic < 9; ++ic)
                    acc += xs[tt * 17 + ic] * cw[(oc * 9 + ic) * 3 + kk];
            }
        }
        acc = fmaxf(acc, 0.f);
        acc = (acc - brm[oc]) * rsqrtf(brv[oc] + EPSF) * bg[oc] + bb[oc];
        ybuf[oc][t] = acc;
    }
    __syncthreads();

    for (int i = tid; i < TT * 24; i += 256) {
        int u = i / 24, oc = i % 24;
        feat[u][oc] = fmaxf(ybuf[oc][2 * u], ybuf[oc][2 * u + 1]);
    }
    for (int i = tid; i < TT * 20; i += 256) {
        int u = i / 20, oc = i % 20;
        float acc = compb[oc];
        #pragma unroll
        for (int j = 0; j < 8; ++j) acc += xs[u * 17 + 9 + j] * compw[oc * 8 + j];
        feat[u][24 + oc] = fmaxf(acc, 0.f);
    }
    __syncthreads();

    for (int i = tid; i < TT * FEATK; i += 256) {
        int u = i >> 6, c = i & 63;
        float v = (c < 44) ? feat[u][c] : 0.f;
        feat_out[((long)b * TT + u) * FEATK + c] = __float2bfloat16(v);
    }
}

// ---------------------------------------------------------------------------
// bf16 MFMA GEMM core (BK=64, proven): C = A @ W^T + bias. R5 swizzle (0
// conflicts), plain epilogue stores (R7: never NT-store scattered narrow).
// ---------------------------------------------------------------------------
template <int WRITE_BF16>
__device__ __forceinline__
void gemm_core(const __hip_bfloat16* __restrict__ A0, int lda0,
               const __hip_bfloat16* __restrict__ A1, int lda1, int ksplit,
               const __hip_bfloat16* __restrict__ W, int ldw,
               const float* __restrict__ bias,
               void* __restrict__ Cout, int ldc, int K, int bx, int by) {
    __shared__ __hip_bfloat16 As[128 * 64];
    __shared__ __hip_bfloat16 Bs[128 * 64];
    const int tid = threadIdx.x;
    const int wave = tid >> 6, lane = tid & 63;
    const long m0 = (long)by * 128;
    const long n0 = (long)bx * 128;

    f32x4 acc[4][4] = {};

    for (int k0 = 0; k0 < K; k0 += 64) {
        __syncthreads();
        #pragma unroll
        for (int it = 0; it < 4; ++it) {
            int id = it * 256 + tid;
            int row = id >> 3;
            int kc = ((id & 7) ^ (row & 7)) << 3;
            int gk = k0 + kc;
            const __hip_bfloat16* srcA;
            if (gk < ksplit) srcA = A0 + (m0 + row) * (long)lda0 + gk;
            else             srcA = A1 + (m0 + row) * (long)lda1 + (gk - ksplit);
            async_load16(srcA, &As[id * 8]);
            const __hip_bfloat16* srcB = W + (n0 + row) * (long)ldw + gk;
            async_load16(srcB, &Bs[id * 8]);
        }
        __syncthreads();
        #pragma unroll
        for (int ks = 0; ks < 2; ++ks) {
            const int kb = ((ks * 4 + (lane >> 4)) ^ (lane & 7)) << 3;
            const int ar = (wave >> 1) * 64 + (lane & 15);
            const int br = (wave & 1) * 64 + (lane & 15);
            bf16x8 afr[4], bfr[4];
            #pragma unroll
            for (int i = 0; i < 4; ++i) afr[i] = *(const bf16x8*)&As[(ar + i * 16) * 64 + kb];
            #pragma unroll
            for (int i = 0; i < 4; ++i) bfr[i] = *(const bf16x8*)&Bs[(br + i * 16) * 64 + kb];
            #pragma unroll
            for (int mi = 0; mi < 4; ++mi)
                #pragma unroll
                for (int ni = 0; ni < 4; ++ni)
                    acc[mi][ni] = __builtin_amdgcn_mfma_f32_16x16x32_bf16(afr[mi], bfr[ni], acc[mi][ni], 0, 0, 0);
        }
    }

    const int cr = (lane >> 4) * 4;
    const int ccol = lane & 15;
    #pragma unroll
    for (int ni = 0; ni < 4; ++ni) {
        long col = n0 + (wave & 1) * 64 + ni * 16 + ccol;
        float bv = bias ? bias[col] : 0.f;
        #pragma unroll
        for (int mi = 0; mi < 4; ++mi) {
            long rowb = m0 + (wave >> 1) * 64 + mi * 16 + cr;
            #pragma unroll
            for (int r = 0; r < 4; ++r) {
                float v = acc[mi][ni][r] + bv;
                if (WRITE_BF16)
                    ((__hip_bfloat16*)Cout)[(rowb + r) * (long)ldc + col] = __float2bfloat16(v);
                else
                    ((float*)Cout)[(rowb + r) * (long)ldc + col] = v;
            }
        }
    }
}

template <int WRITE_BF16>
__global__ __launch_bounds__(256)
void gemm_bias(const __hip_bfloat16* __restrict__ A0, int lda0,
               const __hip_bfloat16* __restrict__ A1, int lda1, int ksplit,
               const __hip_bfloat16* __restrict__ W, int ldw,
               const float* __restrict__ bias,
               void* __restrict__ Cout, int ldc, int K) {
    gemm_core<WRITE_BF16>(A0, lda0, A1, lda1, ksplit, W, ldw, bias, Cout, ldc, K,
                          blockIdx.x, blockIdx.y);
}

// ---------------------------------------------------------------------------
// R9: dual gate GEMM, single-barrier double-buffered BK=32 pipeline.
// Structure: stage(buf0); loop{ barrier; stage(buf_next); compute(buf_cur) }.
// The compiler's vmcnt(0)-before-s_barrier now drains loads issued one full
// compute-phase earlier instead of just-issued ones -> latency overlapped.
// Same 32 KB LDS (5 blocks/CU), same barrier count as BK=64 two-barrier.
// Swizzle for 32-wide slab: chunk c stored at c^((row>>1)&3); read offset
// (lane>>4)^((lane>>1)&3) -> 8 lanes per 4-bank group (even, conflict-free).
// Keeps R8 2D XCD partition (verified: FETCH 120 -> 42-59 MB).
// ---------------------------------------------------------------------------
template <int WRITE_BF16>
__global__ __launch_bounds__(256)
void gemm_dual_db(const __hip_bfloat16* A0a, int lda0a, const __hip_bfloat16* A1a,
                  int lda1a, int Ka, const __hip_bfloat16* Wa,
                  const float* biasa, void* Ca,
                  const __hip_bfloat16* A0b, int lda0b, const __hip_bfloat16* A1b,
                  int lda1b, int Kb, const __hip_bfloat16* Wb,
                  const float* biasb, void* Cb,
                  int ksplit, int ldw, int ldc) {
    const int id = blockIdx.x;
    const int xcd = id & 7;
    const int mhalf = xcd >> 2;
    const int czg = xcd & 3;
    const int rest = id >> 3;
    const int m = mhalf * 16 + (rest & 15);
    const int colz = czg * 10 + (rest >> 4);
    const int col = colz % 20;
    const int z = colz / 20;
    const __hip_bfloat16* A0 = z ? A0b : A0a;
    const __hip_bfloat16* A1 = z ? A1b : A1a;
    const __hip_bfloat16* W  = z ? Wb  : Wa;
    const float* bias        = z ? biasb : biasa;
    void* Cout               = z ? Cb : Ca;
    int lda0 = z ? lda0b : lda0a;
    int lda1 = z ? lda1b : lda1a;
    int K    = z ? Kb : Ka;

    __shared__ __hip_bfloat16 As[2][128 * 32];
    __shared__ __hip_bfloat16 Bs[2][128 * 32];
    const int tid = threadIdx.x;
    const int wave = tid >> 6, lane = tid & 63;
    const long m0 = (long)m * 128;
    const long n0 = (long)col * 128;

    f32x4 acc[4][4] = {};

    auto stage = [&](int hb, int k0) {
        #pragma unroll
        for (int it = 0; it < 2; ++it) {
            int sid = it * 256 + tid;              // 0..511
            int row = sid >> 2;                    // 0..127
            int kc = ((sid & 3) ^ ((row >> 1) & 3)) << 3;
            int gk = k0 + kc;
            const __hip_bfloat16* srcA;
            if (gk < ksplit) srcA = A0 + (m0 + row) * (long)lda0 + gk;
            else             srcA = A1 + (m0 + row) * (long)lda1 + (gk - ksplit);
            async_load16(srcA, &As[hb][sid * 8]);
            const __hip_bfloat16* srcB = W + (n0 + row) * (long)ldw + gk;
            async_load16(srcB, &Bs[hb][sid * 8]);
        }
    };

    stage(0, 0);
    const int nslab = K >> 5;
    const int kb = ((lane >> 4) ^ ((lane >> 1) & 3)) << 3;
    const int ar = (wave >> 1) * 64 + (lane & 15);
    const int br = (wave & 1) * 64 + (lane & 15);

    for (int kk = 0; kk < nslab; ++kk) {
        const int hb = kk & 1;
        __syncthreads();                            // drains stage(kk-1)
        if (kk + 1 < nslab) stage(hb ^ 1, (kk + 1) << 5);
        bf16x8 afr[4], bfr[4];
        #pragma unroll
        for (int i = 0; i < 4; ++i) afr[i] = *(const bf16x8*)&As[hb][(ar + i * 16) * 32 + kb];
        #pragma unroll
        for (int i = 0; i < 4; ++i) bfr[i] = *(const bf16x8*)&Bs[hb][(br + i * 16) * 32 + kb];
        #pragma unroll
        for (int mi = 0; mi < 4; ++mi)
            #pragma unroll
            for (int ni = 0; ni < 4; ++ni)
                acc[mi][ni] = __builtin_amdgcn_mfma_f32_16x16x32_bf16(afr[mi], bfr[ni], acc[mi][ni], 0, 0, 0);
    }

    const int cr = (lane >> 4) * 4;
    const int ccol = lane & 15;
    #pragma unroll
    for (int ni = 0; ni < 4; ++ni) {
        long ccol2 = n0 + (wave & 1) * 64 + ni * 16 + ccol;
        float bv = bias ? bias[ccol2] : 0.f;
        #pragma unroll
        for (int mi = 0; mi < 4; ++mi) {
            long rowb = m0 + (wave >> 1) * 64 + mi * 16 + cr;
            #pragma unroll
            for (int r = 0; r < 4; ++r) {
                float v = acc[mi][ni][r] + bv;
                if (WRITE_BF16)
                    ((__hip_bfloat16*)Cout)[(rowb + r) * (long)ldc + ccol2] = __float2bfloat16(v);
                else
                    ((float*)Cout)[(rowb + r) * (long)ldc + ccol2] = v;
            }
        }
    }
}

// ---------------------------------------------------------------------------
// Gate elementwise + the two LayerNorms.
// ---------------------------------------------------------------------------
__device__ __forceinline__ void block_reduce2(float& a, float& b, float* red) {
    #pragma unroll
    for (int off = 32; off > 0; off >>= 1) {
        a += __shfl_down(a, off, 64);
        b += __shfl_down(b, off, 64);
    }
    int lane = threadIdx.x & 63, w = threadIdx.x >> 6;
    if (lane == 0) { red[w] = a; red[8 + w] = b; }
    __syncthreads();
    a = red[0] + red[1] + red[2] + red[3];
    b = red[8] + red[9] + red[10] + red[11];
    __syncthreads();
}

__device__ __forceinline__
void gate_ew_body(const __hip_bfloat16* __restrict__ g, float* __restrict__ c,
                  const float* __restrict__ ret,
                  const float* __restrict__ elg, const float* __restrict__ elb,
                  const float* __restrict__ lng, const float* __restrict__ lnb,
                  __hip_bfloat16* __restrict__ hout, long hstride, int b) {
    const int tid = threadIdx.x;
    const __hip_bfloat16* gr = g + (long)b * NGATE_;
    __shared__ float red[16];

    float o_[2], cn_[2];
    float s = 0.f, s2 = 0.f;
    #pragma unroll
    for (int u = 0; u < 2; ++u) {
        int j = tid + u * 256;
        float fg = __bfloat162float(gr[j]);
        float ig = __bfloat162float(gr[512 + j]);
        float og = __bfloat162float(gr[1024 + j]);
        float cg = __bfloat162float(gr[1536 + j]);
        float mg = __bfloat162float(gr[2048 + j]);
        float f = sigmoidf_(fg), i = sigmoidf_(ig), o = sigmoidf_(og);
        float cc = tanhf(cg), m = sigmoidf_(mg);
        float cold = c[(long)b * H_ + j];
        float r = ret[j];
        float cn = f * cold + i * cc;
        cn = cn * r + (1.f - r) * cold;
        cn = m * cn + (1.f - m) * cold;
        c[(long)b * H_ + j] = cn;
        o_[u] = o; cn_[u] = cn;
        s += o; s2 += o * o;
    }
    block_reduce2(s, s2, red);
    float mean = s * (1.f / H_);
    float var = s2 * (1.f / H_) - mean * mean;
    float rstd = rsqrtf(var + EPSF);

    float val[2];
    float s3 = 0.f, s4 = 0.f;
    #pragma unroll
    for (int u = 0; u < 2; ++u) {
        int j = tid + u * 256;
        float on = (o_[u] - mean) * rstd * elg[j] + elb[j];
        float oe = sigmoidf_(on);
        float v = oe * tanhf(cn_[u]);
        val[u] = v; s3 += v; s4 += v * v;
    }
    block_reduce2(s3, s4, red);
    float mean2 = s3 * (1.f / H_);
    float var2 = s4 * (1.f / H_) - mean2 * mean2;
    float rstd2 = rsqrtf(var2 + EPSF);
    #pragma unroll
    for (int u = 0; u < 2; ++u) {
        int j = tid + u * 256;
        float h = (val[u] - mean2) * rstd2 * lng[j] + lnb[j];
        hout[(long)b * hstride + j] = __float2bfloat16(h);
    }
}

__global__ __launch_bounds__(256)
void gate_ew(const __hip_bfloat16* __restrict__ g, float* __restrict__ c,
             const float* __restrict__ ret,
             const float* __restrict__ elg, const float* __restrict__ elb,
             const float* __restrict__ lng, const float* __restrict__ lnb,
             __hip_bfloat16* __restrict__ hout, long hstride) {
    gate_ew_body(g, c, ret, elg, elb, lng, lnb, hout, hstride, blockIdx.x);
}

__global__ __launch_bounds__(256)
void gate_ew_dual(const __hip_bfloat16* ga, float* ca, const float* reta,
                  const float* elga, const float* elba,
                  const float* lnga, const float* lnba,
                  __hip_bfloat16* houta, long hstridea,
                  const __hip_bfloat16* gb, float* cb, const float* retb,
                  const float* elgb, const float* elbb,
                  const float* lngb, const float* lnbb,
                  __hip_bfloat16* houtb, long hstrideb) {
    int bid = blockIdx.x;
    bool isB = bid >= B_;
    int b = isB ? bid - B_ : bid;
    const __hip_bfloat16* g = isB ? gb : ga;
    float* c        = isB ? cb : ca;
    const float* ret = isB ? retb : reta;
    const float* elg = isB ? elgb : elga;
    const float* elb = isB ? elbb : elba;
    const float* lng = isB ? lngb : lnga;
    const float* lnb = isB ? lnbb : lnba;
    __hip_bfloat16* hout = isB ? houtb : houta;
    long hstride = isB ? hstrideb : hstridea;
    gate_ew_body(g, c, ret, elg, elb, lng, lnb, hout, hstride, b);
}

// ---------------------------------------------------------------------------
// R9 fused attention: per batch row, scores = U.seq (k-bias is softmax-
// invariant), softmax over 30, sbar_h = sum_t p_t seq_t. One block per b;
// seq row (30 KB) + U(b) (4 KB) in LDS; wave h handles head h, lane owns
// 8 columns; 30-score butterfly reduce across 64 lanes.
// ---------------------------------------------------------------------------
__global__ __launch_bounds__(256)
void attn_fused(const __hip_bfloat16* __restrict__ seq,
                const __hip_bfloat16* __restrict__ U,
                __hip_bfloat16* __restrict__ sbar) {
    const int b = blockIdx.x, tid = threadIdx.x;
    __shared__ __hip_bfloat16 seq_s[TT * H_];   // 30 KB
    __shared__ __hip_bfloat16 U_s[NH_ * H_];    // 4 KB
    {
        const bf16x8* sp = (const bf16x8*)(seq + (size_t)b * TT * H_);
        bf16x8* dp = (bf16x8*)seq_s;
        for (int i = tid; i < TT * H_ / 8; i += 256) dp[i] = sp[i];
        ((bf16x8*)U_s)[tid] = ((const bf16x8*)(U + (size_t)b * NH_ * H_))[tid];
    }
    __syncthreads();
    const int h = tid >> 6, lane = tid & 63;
    const int c0 = lane * 8;
    float uq[8];
    {
        bf16x8 uv = *(const bf16x8*)&U_s[h * H_ + c0];
        #pragma unroll
        for (int j = 0; j < 8; ++j) uq[j] = bf2f(uv[j]);
    }
    float p[TT];
    #pragma unroll
    for (int t = 0; t < TT; ++t) {
        bf16x8 sv = *(const bf16x8*)&seq_s[t * H_ + c0];
        float a = 0.f;
        #pragma unroll
        for (int j = 0; j < 8; ++j) a += uq[j] * bf2f(sv[j]);
        p[t] = a;
    }
    #pragma unroll
    for (int off = 32; off > 0; off >>= 1) {
        #pragma unroll
        for (int t = 0; t < TT; ++t) p[t] += __shfl_xor(p[t], off);
    }
    const float scale = 0.08838834764831845f;   // 1/sqrt(128)
    float mx = -1e30f;
    #pragma unroll
    for (int t = 0; t < TT; ++t) { p[t] *= scale; mx = fmaxf(mx, p[t]); }
    float den = 0.f;
    #pragma unroll
    for (int t = 0; t < TT; ++t) { p[t] = __expf(p[t] - mx); den += p[t]; }
    float inv = 1.f / den;
    float accv[8] = {};
    #pragma unroll
    for (int t = 0; t < TT; ++t) {
        float w = p[t] * inv;
        bf16x8 sv = *(const bf16x8*)&seq_s[t * H_ + c0];
        #pragma unroll
        for (int j = 0; j < 8; ++j) accv[j] += w * bf2f(sv[j]);
    }
    bf16x8 outv;
    #pragma unroll
    for (int j = 0; j < 8; ++j) {
        __hip_bfloat16 hv = __float2bfloat16(accv[j]);
        outv[j] = *(short*)&hv;
    }
    *(bf16x8*)&sbar[(size_t)b * (NH_ * H_) + h * H_ + c0] = outv;
}

// ---------------------------------------------------------------------------
// Head: bn2 on latent then out (128->14). One block (128 thr) per batch row.
// ---------------------------------------------------------------------------
__global__ __launch_bounds__(128)
void head_kernel(const float* __restrict__ lat_in,
                 const float* __restrict__ g2, const float* __restrict__ b2,
                 const float* __restrict__ rm2, const float* __restrict__ rv2,
                 const float* __restrict__ ow, const float* __restrict__ ob,
                 float* __restrict__ out) {
    const int b = blockIdx.x, tid = threadIdx.x;
    __shared__ float ls[LAT_];
    float a = lat_in[(long)b * LAT_ + tid];
    ls[tid] = (a - rm2[tid]) * rsqrtf(rv2[tid] + EPSF) * g2[tid] + b2[tid];
    __syncthreads();
    if (tid < OUT_) {
        float acc = ob[tid];
        #pragma unroll 4
        for (int j = 0; j < LAT_; ++j) acc += ls[j] * ow[tid * LAT_ + j];
        out[(long)b * OUT_ + tid] = acc;
    }
}

// ---------------------------------------------------------------------------
extern "C" void kernel_launch(void* const* d_in, const int* in_sizes, int n_in,
                              void* d_out, int out_size, void* d_ws, size_t ws_size,
                              hipStream_t stream) {
    const float* x        = (const float*)d_in[0];
    const float* conv1_w  = (const float*)d_in[1];
    const float* conv1_b  = (const float*)d_in[2];
    const float* bn1_g    = (const float*)d_in[3];
    const float* bn1_b    = (const float*)d_in[4];
    const float* bn1_rm   = (const float*)d_in[5];
    const float* bn1_rv   = (const float*)d_in[6];
    const float* comp_w   = (const float*)d_in[7];
    const float* comp_b   = (const float*)d_in[8];
    const float* proj_w   = (const float*)d_in[9];
    const float* proj_b   = (const float*)d_in[10];
    const float* gates_w  = (const float*)d_in[11];
    const float* gates_b  = (const float*)d_in[12];
    const float* retention= (const float*)d_in[13];
    const float* expln_g  = (const float*)d_in[14];
    const float* expln_b  = (const float*)d_in[15];
    const float* ln_g     = (const float*)d_in[16];
    const float* ln_b     = (const float*)d_in[17];
    const float* attn_in_w  = (const float*)d_in[18];
    const float* attn_in_b  = (const float*)d_in[19];
    const float* attn_out_w = (const float*)d_in[20];
    const float* attn_out_b = (const float*)d_in[21];
    const float* bneck_w  = (const float*)d_in[22];
    const float* bneck_b  = (const float*)d_in[23];
    const float* bn2_g    = (const float*)d_in[24];
    const float* bn2_b    = (const float*)d_in[25];
    const float* bn2_rm   = (const float*)d_in[26];
    const float* bn2_rv   = (const float*)d_in[27];
    const float* out_w    = (const float*)d_in[28];
    const float* out_b    = (const float*)d_in[29];
    float* out = (float*)d_out;

    // ---- workspace layout (~220 MiB) ----
    char* base = (char*)d_ws;
    size_t off = 0;
    auto alloc = [&](size_t nbytes) -> char* {
        char* p = base + off;
        off += (nbytes + 255) & ~(size_t)255;
        return p;
    };
    __hip_bfloat16* seq_bf = (__hip_bfloat16*)alloc((size_t)B_ * TT * H_ * 2);   // 126 MB
    // union (42 MB): feat / 2x gate buffers (scan) / U+sbar+wkd+wvd (attn)
    size_t g_bytes = (size_t)B_ * NGATE_ * 2;                                    // 21 MB
    char* un = alloc(2 * g_bytes);
    __hip_bfloat16* feat_bf = (__hip_bfloat16*)un;
    __hip_bfloat16* gA_bf   = (__hip_bfloat16*)un;
    __hip_bfloat16* gB_bf   = (__hip_bfloat16*)(un + g_bytes);
    __hip_bfloat16* U_bf    = (__hip_bfloat16*)un;                               // 16 MB
    __hip_bfloat16* sbar_bf = (__hip_bfloat16*)(un + (size_t)16 * 1024 * 1024);  // 16 MB
    __hip_bfloat16* wkd_bf  = (__hip_bfloat16*)(un + (size_t)32 * 1024 * 1024);  // 2 MB
    __hip_bfloat16* wvd_bf  = (__hip_bfloat16*)(un + (size_t)35 * 1024 * 1024);  // 2 MB
    float*          c0    = (float*)alloc((size_t)B_ * H_ * 4);
    float*          c1    = (float*)alloc((size_t)B_ * H_ * 4);
    __hip_bfloat16* h0_bf = (__hip_bfloat16*)alloc((size_t)B_ * H_ * 2);
    __hip_bfloat16* q_bf  = (__hip_bfloat16*)alloc((size_t)B_ * H_ * 2);  // also fin
    __hip_bfloat16* fin_bf = q_bf;
    __hip_bfloat16* av_bf = (__hip_bfloat16*)alloc((size_t)B_ * H_ * 2);
    float*          lat_f = (float*)alloc((size_t)B_ * LAT_ * 4);
    __hip_bfloat16* gw_bf = (__hip_bfloat16*)alloc((size_t)L_ * 5 * H_ * 2 * H_ * 2);
    __hip_bfloat16* ai_bf = (__hip_bfloat16*)alloc((size_t)H_ * H_ * 2);  // q rows only
    __hip_bfloat16* ao_bf = (__hip_bfloat16*)alloc((size_t)H_ * H_ * 2);
    __hip_bfloat16* pw_bf = (__hip_bfloat16*)alloc((size_t)H_ * FEATK * 2);
    __hip_bfloat16* bw_bf = (__hip_bfloat16*)alloc((size_t)LAT_ * H_ * 2);
    (void)ws_size; (void)in_sizes; (void)n_in; (void)out_size;

    // ---- weight conversion + state zeroing ----
    cvt_bf16<<<2048, 256, 0, stream>>>(gates_w, gw_bf, (long)L_ * 5 * H_ * 2 * H_);
    cvt_bf16<<<256, 256, 0, stream>>>(attn_in_w, ai_bf, (long)H_ * H_);
    cvt_bf16<<<256, 256, 0, stream>>>(attn_out_w, ao_bf, (long)H_ * H_);
    cvt_bf16<<<64, 256, 0, stream>>>(bneck_w, bw_bf, (long)LAT_ * H_);
    pad_projw<<<(H_ * FEATK + 255) / 256, 256, 0, stream>>>(proj_w, pw_bf);
    zero_f32<<<2048, 256, 0, stream>>>(c0, (long)2 * B_ * H_);

    // ---- front-end: feat, then proj via MFMA GEMM ----
    frontend_kernel<<<B_, 256, 0, stream>>>(x, conv1_w, conv1_b, bn1_g, bn1_b, bn1_rm,
                                            bn1_rv, comp_w, comp_b, feat_bf);
    gemm_bias<1><<<dim3(H_ / 128, (B_ * TT) / 128), 256, 0, stream>>>(
        feat_bf, FEATK, (const __hip_bfloat16*)nullptr, 0, FEATK,
        pw_bf, FEATK, proj_b, (void*)seq_bf, H_, FEATK);

    // ---- recurrent scan (layer1(t) || layer0(t+1) dual pipeline) ----
    const int WL = 5 * H_ * 2 * H_;
    const dim3 ggrid(NGATE_ / 128, B_ / 128);

    gemm_bias<1><<<ggrid, 256, 0, stream>>>(
        seq_bf, TT * H_, (const __hip_bfloat16*)nullptr, 0, H_,
        gw_bf, 2 * H_, gates_b, (void*)gB_bf, NGATE_, H_);
    gate_ew<<<B_, 256, 0, stream>>>(gB_bf, c0, retention, expln_g, expln_b,
                                    ln_g, ln_b, h0_bf, H_);

    for (int t = 0; t < TT - 1; ++t) {
        gemm_dual_db<1><<<1280, 256, 0, stream>>>(
            h0_bf, H_, (t == 0) ? (const __hip_bfloat16*)nullptr
                                : seq_bf + (size_t)(t - 1) * H_,
            TT * H_, (t == 0) ? H_ : 2 * H_, gw_bf + WL, gates_b + NGATE_, (void*)gA_bf,
            seq_bf + (size_t)(t + 1) * H_, TT * H_, h0_bf, H_, 2 * H_,
            gw_bf, gates_b, (void*)gB_bf,
            H_, 2 * H_, NGATE_);
        gate_ew_dual<<<2 * B_, 256, 0, stream>>>(
            gA_bf, c1, retention + H_, expln_g + H_, expln_b + H_,
            ln_g + H_, ln_b + H_, seq_bf + (size_t)t * H_, TT * H_,
            gB_bf, c0, retention, expln_g, expln_b,
            ln_g, ln_b, h0_bf, H_);
    }
    gemm_bias<1><<<ggrid, 256, 0, stream>>>(
        h0_bf, H_, seq_bf + (size_t)(TT - 2) * H_, TT * H_, H_,
        gw_bf + WL, 2 * H_, gates_b + NGATE_, (void*)gA_bf, NGATE_, 2 * H_);
    gate_ew<<<B_, 256, 0, stream>>>(gA_bf, c1, retention + H_, expln_g + H_,
                                    expln_b + H_, ln_g + H_, ln_b + H_,
                                    seq_bf + (size_t)(TT - 1) * H_, TT * H_);

    // ---- attention (restructured): build block-diag weights in freed union ----
    build_wkd<<<4096, 256, 0, stream>>>(attn_in_w, wkd_bf);
    build_wvd<<<4096, 256, 0, stream>>>(attn_in_w, wvd_bf);

    // q projection (last timestep) -> bf16
    gemm_bias<1><<<dim3(H_ / 128, B_ / 128), 256, 0, stream>>>(
        seq_bf + (size_t)29 * H_, TT * H_, (const __hip_bfloat16*)nullptr, 0, H_,
        ai_bf, H_, attn_in_b, (void*)q_bf, H_, H_);

    // U = q @ wkd^T  [4096, 2048]
    gemm_bias<1><<<dim3(2048 / 128, B_ / 128), 256, 0, stream>>>(
        q_bf, H_, (const __hip_bfloat16*)nullptr, 0, H_,
        wkd_bf, H_, (const float*)nullptr, (void*)U_bf, 2048, H_);

    // fused scores/softmax/weighted-sum -> sbar [4096, 2048]
    attn_fused<<<B_, 256, 0, stream>>>(seq_bf, U_bf, sbar_bf);

    // o = sbar @ wvd^T + bv -> av [4096, 512]
    gemm_bias<1><<<dim3(H_ / 128, B_ / 128), 256, 0, stream>>>(
        sbar_bf, 2048, (const __hip_bfloat16*)nullptr, 0, 2048,
        wvd_bf, 2048, attn_in_b + 2 * H_, (void*)av_bf, H_, 2048);

    // attn_out projection -> bf16 fin (aliases q_bf; q fully consumed)
    gemm_bias<1><<<dim3(H_ / 128, B_ / 128), 256, 0, stream>>>(
        av_bf, H_, (const __hip_bfloat16*)nullptr, 0, H_,
        ao_bf, H_, attn_out_b, (void*)fin_bf, H_, H_);

    // ---- bneck GEMM -> latent f32, then bn2+head ----
    gemm_bias<0><<<dim3(LAT_ / 128, B_ / 128), 256, 0, stream>>>(
        fin_bf, H_, (const __hip_bfloat16*)nullptr, 0, H_,
        bw_bf, H_, bneck_b, (void*)lat_f, LAT_, H_);
    head_kernel<<<B_, 128, 0, stream>>>(lat_f, bn2_g, bn2_b, bn2_rm, bn2_rv,
                                        out_w, out_b, out);
}

// Round 11
// 2769.572 us; speedup vs baseline: 1.4467x; 1.0409x over previous
//
#include <hip/hip_runtime.h>
#include <hip/hip_bf16.h>

// Problem constants
#define B_   4096
#define T_   60
#define TT   30          // pooled sequence length
#define H_   512
#define L_   2
#define NH_  4
#define DH_  128
#define LAT_ 128
#define OUT_ 14
#define NGATE_ (5*H_)    // 2560
#define EPSF 1e-5f
#define FEATK 64         // feat padded to 64 (GEMM K granularity)

typedef __attribute__((ext_vector_type(8))) short bf16x8;
typedef __attribute__((ext_vector_type(4))) float f32x4;

__device__ __forceinline__ float sigmoidf_(float x) { return 1.0f / (1.0f + __expf(-x)); }
__device__ __forceinline__ float bf2f(short s) {
    return __uint_as_float(((unsigned)(unsigned short)s) << 16);
}

__device__ __forceinline__ void async_load16(const void* g, void* l) {
    __builtin_amdgcn_global_load_lds((const __attribute__((address_space(1))) void*)g,
                                     (__attribute__((address_space(3))) void*)l, 16, 0, 0);
}

// ---------------------------------------------------------------------------
// Utility kernels
// ---------------------------------------------------------------------------
__global__ __launch_bounds__(256) void cvt_bf16(const float* __restrict__ in,
                                                __hip_bfloat16* __restrict__ out, long n) {
    long i = (long)blockIdx.x * blockDim.x + threadIdx.x;
    long stride = (long)gridDim.x * blockDim.x;
    for (; i < n; i += stride) out[i] = __float2bfloat16(in[i]);
}

__global__ __launch_bounds__(256) void zero_f32(float* __restrict__ p, long n) {
    long i = (long)blockIdx.x * blockDim.x + threadIdx.x;
    long stride = (long)gridDim.x * blockDim.x;
    for (; i < n; i += stride) p[i] = 0.0f;
}

// proj_w [512,44] f32 -> padded [512,64] bf16 (cols 44..63 zero)
__global__ __launch_bounds__(256) void pad_projw(const float* __restrict__ pw,
                                                 __hip_bfloat16* __restrict__ out) {
    int i = blockIdx.x * 256 + threadIdx.x;
    if (i >= H_ * FEATK) return;
    int r = i >> 6, c = i & 63;
    out[i] = __float2bfloat16(c < 44 ? pw[r * 44 + c] : 0.f);
}

// Block-diagonal W_k^T: wkd[n=h*512+i, k] = W_k[k,i] if k in h's 128-slice.
// U[b,n] = sum_k q[b,k] * wkd[n,k]  ->  score(b,h,t) = U(b,h,:).seq(b,t,:)
__global__ __launch_bounds__(256)
void build_wkd(const float* __restrict__ aiw, __hip_bfloat16* __restrict__ wkd) {
    int i = blockIdx.x * 256 + threadIdx.x;          // 2048*512
    if (i >= 2048 * 512) return;
    int n = i >> 9, k = i & 511;
    float v = ((k >> 7) == (n >> 9)) ? aiw[(H_ + k) * H_ + (n & 511)] : 0.f;
    wkd[i] = __float2bfloat16(v);
}

// Block-diagonal W_v: wvd[n, k=h*512+i] = W_v[n,i] if h == n>>7.
// o[b,n] = sum_k sbar[b,k] * wvd[n,k] + bv[n]
__global__ __launch_bounds__(256)
void build_wvd(const float* __restrict__ aiw, __hip_bfloat16* __restrict__ wvd) {
    int i = blockIdx.x * 256 + threadIdx.x;          // 512*2048
    if (i >= 512 * 2048) return;
    int n = i >> 11, k = i & 2047;
    float v = ((k >> 9) == (n >> 7)) ? aiw[(2 * H_ + n) * H_ + (k & 511)] : 0.f;
    wvd[i] = __float2bfloat16(v);
}

// ---------------------------------------------------------------------------
// Front-end: conv1d(9->24,k3,p1)+relu+bn -> maxpool2 -> concat comp(8->20 relu)
// ---------------------------------------------------------------------------
__global__ __launch_bounds__(256)
void frontend_kernel(const float* __restrict__ x,
                     const float* __restrict__ cw, const float* __restrict__ cb,
                     const float* __restrict__ bg, const float* __restrict__ bb,
                     const float* __restrict__ brm, const float* __restrict__ brv,
                     const float* __restrict__ compw, const float* __restrict__ compb,
                     __hip_bfloat16* __restrict__ feat_out) {
    const int b = blockIdx.x, tid = threadIdx.x;
    __shared__ float xs[T_ * 17];
    __shared__ float ybuf[24][T_];
    __shared__ float feat[TT][44];

    for (int i = tid; i < T_ * 17; i += 256) xs[i] = x[(long)b * T_ * 17 + i];
    __syncthreads();

    for (int i = tid; i < 24 * T_; i += 256) {
        int oc = i / T_, t = i % T_;
        float acc = cb[oc];
        #pragma unroll
        for (int kk = 0; kk < 3; ++kk) {
            int tt = t + kk - 1;
            if (tt >= 0 && tt < T_) {
                #pragma unroll
                for (int ic = 0; ic < 9; ++ic)
                    acc += xs[tt * 17 + ic] * cw[(oc * 9 + ic) * 3 + kk];
            }
        }
        acc = fmaxf(acc, 0.f);
        acc = (acc - brm[oc]) * rsqrtf(brv[oc] + EPSF) * bg[oc] + bb[oc];
        ybuf[oc][t] = acc;
    }
    __syncthreads();

    for (int i = tid; i < TT * 24; i += 256) {
        int u = i / 24, oc = i % 24;
        feat[u][oc] = fmaxf(ybuf[oc][2 * u], ybuf[oc][2 * u + 1]);
    }
    for (int i = tid; i < TT * 20; i += 256) {
        int u = i / 20, oc = i % 20;
        float acc = compb[oc];
        #pragma unroll
        for (int j = 0; j < 8; ++j) acc += xs[u * 17 + 9 + j] * compw[oc * 8 + j];
        feat[u][24 + oc] = fmaxf(acc, 0.f);
    }
    __syncthreads();

    for (int i = tid; i < TT * FEATK; i += 256) {
        int u = i >> 6, c = i & 63;
        float v = (c < 44) ? feat[u][c] : 0.f;
        feat_out[((long)b * TT + u) * FEATK + c] = __float2bfloat16(v);
    }
}

// ---------------------------------------------------------------------------
// bf16 MFMA GEMM core (BK=64, proven): C = A @ W^T + bias. R5 swizzle (0
// conflicts), plain epilogue stores (R7: never NT-store scattered narrow).
// ---------------------------------------------------------------------------
template <int WRITE_BF16>
__device__ __forceinline__
void gemm_core(const __hip_bfloat16* __restrict__ A0, int lda0,
               const __hip_bfloat16* __restrict__ A1, int lda1, int ksplit,
               const __hip_bfloat16* __restrict__ W, int ldw,
               const float* __restrict__ bias,
               void* __restrict__ Cout, int ldc, int K, int bx, int by) {
    __shared__ __hip_bfloat16 As[128 * 64];
    __shared__ __hip_bfloat16 Bs[128 * 64];
    const int tid = threadIdx.x;
    const int wave = tid >> 6, lane = tid & 63;
    const long m0 = (long)by * 128;
    const long n0 = (long)bx * 128;

    f32x4 acc[4][4] = {};

    for (int k0 = 0; k0 < K; k0 += 64) {
        __syncthreads();
        #pragma unroll
        for (int it = 0; it < 4; ++it) {
            int id = it * 256 + tid;
            int row = id >> 3;
            int kc = ((id & 7) ^ (row & 7)) << 3;
            int gk = k0 + kc;
            const __hip_bfloat16* srcA;
            if (gk < ksplit) srcA = A0 + (m0 + row) * (long)lda0 + gk;
            else             srcA = A1 + (m0 + row) * (long)lda1 + (gk - ksplit);
            async_load16(srcA, &As[id * 8]);
            const __hip_bfloat16* srcB = W + (n0 + row) * (long)ldw + gk;
            async_load16(srcB, &Bs[id * 8]);
        }
        __syncthreads();
        #pragma unroll
        for (int ks = 0; ks < 2; ++ks) {
            const int kb = ((ks * 4 + (lane >> 4)) ^ (lane & 7)) << 3;
            const int ar = (wave >> 1) * 64 + (lane & 15);
            const int br = (wave & 1) * 64 + (lane & 15);
            bf16x8 afr[4], bfr[4];
            #pragma unroll
            for (int i = 0; i < 4; ++i) afr[i] = *(const bf16x8*)&As[(ar + i * 16) * 64 + kb];
            #pragma unroll
            for (int i = 0; i < 4; ++i) bfr[i] = *(const bf16x8*)&Bs[(br + i * 16) * 64 + kb];
            #pragma unroll
            for (int mi = 0; mi < 4; ++mi)
                #pragma unroll
                for (int ni = 0; ni < 4; ++ni)
                    acc[mi][ni] = __builtin_amdgcn_mfma_f32_16x16x32_bf16(afr[mi], bfr[ni], acc[mi][ni], 0, 0, 0);
        }
    }

    const int cr = (lane >> 4) * 4;
    const int ccol = lane & 15;
    #pragma unroll
    for (int ni = 0; ni < 4; ++ni) {
        long col = n0 + (wave & 1) * 64 + ni * 16 + ccol;
        float bv = bias ? bias[col] : 0.f;
        #pragma unroll
        for (int mi = 0; mi < 4; ++mi) {
            long rowb = m0 + (wave >> 1) * 64 + mi * 16 + cr;
            #pragma unroll
            for (int r = 0; r < 4; ++r) {
                float v = acc[mi][ni][r] + bv;
                if (WRITE_BF16)
                    ((__hip_bfloat16*)Cout)[(rowb + r) * (long)ldc + col] = __float2bfloat16(v);
                else
                    ((float*)Cout)[(rowb + r) * (long)ldc + col] = v;
            }
        }
    }
}

template <int WRITE_BF16>
__global__ __launch_bounds__(256)
void gemm_bias(const __hip_bfloat16* __restrict__ A0, int lda0,
               const __hip_bfloat16* __restrict__ A1, int lda1, int ksplit,
               const __hip_bfloat16* __restrict__ W, int ldw,
               const float* __restrict__ bias,
               void* __restrict__ Cout, int ldc, int K) {
    gemm_core<WRITE_BF16>(A0, lda0, A1, lda1, ksplit, W, ldw, bias, Cout, ldc, K,
                          blockIdx.x, blockIdx.y);
}

// ---------------------------------------------------------------------------
// R9: dual gate GEMM, single-barrier double-buffered BK=32 pipeline.
// Structure: stage(buf0); loop{ barrier; stage(buf_next); compute(buf_cur) }.
// Same 32 KB LDS (5 blocks/CU), conflict-free swizzle for the 32-wide slab.
// Keeps R8 2D XCD partition (verified: FETCH 120 -> 42-59 MB).
// ---------------------------------------------------------------------------
template <int WRITE_BF16>
__global__ __launch_bounds__(256)
void gemm_dual_db(const __hip_bfloat16* A0a, int lda0a, const __hip_bfloat16* A1a,
                  int lda1a, int Ka, const __hip_bfloat16* Wa,
                  const float* biasa, void* Ca,
                  const __hip_bfloat16* A0b, int lda0b, const __hip_bfloat16* A1b,
                  int lda1b, int Kb, const __hip_bfloat16* Wb,
                  const float* biasb, void* Cb,
                  int ksplit, int ldw, int ldc) {
    const int id = blockIdx.x;
    const int xcd = id & 7;
    const int mhalf = xcd >> 2;
    const int czg = xcd & 3;
    const int rest = id >> 3;
    const int m = mhalf * 16 + (rest & 15);
    const int colz = czg * 10 + (rest >> 4);
    const int col = colz % 20;
    const int z = colz / 20;
    const __hip_bfloat16* A0 = z ? A0b : A0a;
    const __hip_bfloat16* A1 = z ? A1b : A1a;
    const __hip_bfloat16* W  = z ? Wb  : Wa;
    const float* bias        = z ? biasb : biasa;
    void* Cout               = z ? Cb : Ca;
    int lda0 = z ? lda0b : lda0a;
    int lda1 = z ? lda1b : lda1a;
    int K    = z ? Kb : Ka;

    __shared__ __hip_bfloat16 As[2][128 * 32];
    __shared__ __hip_bfloat16 Bs[2][128 * 32];
    const int tid = threadIdx.x;
    const int wave = tid >> 6, lane = tid & 63;
    const long m0 = (long)m * 128;
    const long n0 = (long)col * 128;

    f32x4 acc[4][4] = {};

    auto stage = [&](int hb, int k0) {
        #pragma unroll
        for (int it = 0; it < 2; ++it) {
            int sid = it * 256 + tid;
            int row = sid >> 2;
            int kc = ((sid & 3) ^ ((row >> 1) & 3)) << 3;
            int gk = k0 + kc;
            const __hip_bfloat16* srcA;
            if (gk < ksplit) srcA = A0 + (m0 + row) * (long)lda0 + gk;
            else             srcA = A1 + (m0 + row) * (long)lda1 + (gk - ksplit);
            async_load16(srcA, &As[hb][sid * 8]);
            const __hip_bfloat16* srcB = W + (n0 + row) * (long)ldw + gk;
            async_load16(srcB, &Bs[hb][sid * 8]);
        }
    };

    stage(0, 0);
    const int nslab = K >> 5;
    const int kb = ((lane >> 4) ^ ((lane >> 1) & 3)) << 3;
    const int ar = (wave >> 1) * 64 + (lane & 15);
    const int br = (wave & 1) * 64 + (lane & 15);

    for (int kk = 0; kk < nslab; ++kk) {
        const int hb = kk & 1;
        __syncthreads();
        if (kk + 1 < nslab) stage(hb ^ 1, (kk + 1) << 5);
        bf16x8 afr[4], bfr[4];
        #pragma unroll
        for (int i = 0; i < 4; ++i) afr[i] = *(const bf16x8*)&As[hb][(ar + i * 16) * 32 + kb];
        #pragma unroll
        for (int i = 0; i < 4; ++i) bfr[i] = *(const bf16x8*)&Bs[hb][(br + i * 16) * 32 + kb];
        #pragma unroll
        for (int mi = 0; mi < 4; ++mi)
            #pragma unroll
            for (int ni = 0; ni < 4; ++ni)
                acc[mi][ni] = __builtin_amdgcn_mfma_f32_16x16x32_bf16(afr[mi], bfr[ni], acc[mi][ni], 0, 0, 0);
    }

    const int cr = (lane >> 4) * 4;
    const int ccol = lane & 15;
    #pragma unroll
    for (int ni = 0; ni < 4; ++ni) {
        long ccol2 = n0 + (wave & 1) * 64 + ni * 16 + ccol;
        float bv = bias ? bias[ccol2] : 0.f;
        #pragma unroll
        for (int mi = 0; mi < 4; ++mi) {
            long rowb = m0 + (wave >> 1) * 64 + mi * 16 + cr;
            #pragma unroll
            for (int r = 0; r < 4; ++r) {
                float v = acc[mi][ni][r] + bv;
                if (WRITE_BF16)
                    ((__hip_bfloat16*)Cout)[(rowb + r) * (long)ldc + ccol2] = __float2bfloat16(v);
                else
                    ((float*)Cout)[(rowb + r) * (long)ldc + ccol2] = v;
            }
        }
    }
}

// ---------------------------------------------------------------------------
// Gate elementwise + the two LayerNorms.
// ---------------------------------------------------------------------------
__device__ __forceinline__ void block_reduce2(float& a, float& b, float* red) {
    #pragma unroll
    for (int off = 32; off > 0; off >>= 1) {
        a += __shfl_down(a, off, 64);
        b += __shfl_down(b, off, 64);
    }
    int lane = threadIdx.x & 63, w = threadIdx.x >> 6;
    if (lane == 0) { red[w] = a; red[8 + w] = b; }
    __syncthreads();
    a = red[0] + red[1] + red[2] + red[3];
    b = red[8] + red[9] + red[10] + red[11];
    __syncthreads();
}

__device__ __forceinline__
void gate_ew_body(const __hip_bfloat16* __restrict__ g, float* __restrict__ c,
                  const float* __restrict__ ret,
                  const float* __restrict__ elg, const float* __restrict__ elb,
                  const float* __restrict__ lng, const float* __restrict__ lnb,
                  __hip_bfloat16* __restrict__ hout, long hstride, int b) {
    const int tid = threadIdx.x;
    const __hip_bfloat16* gr = g + (long)b * NGATE_;
    __shared__ float red[16];

    float o_[2], cn_[2];
    float s = 0.f, s2 = 0.f;
    #pragma unroll
    for (int u = 0; u < 2; ++u) {
        int j = tid + u * 256;
        float fg = __bfloat162float(gr[j]);
        float ig = __bfloat162float(gr[512 + j]);
        float og = __bfloat162float(gr[1024 + j]);
        float cg = __bfloat162float(gr[1536 + j]);
        float mg = __bfloat162float(gr[2048 + j]);
        float f = sigmoidf_(fg), i = sigmoidf_(ig), o = sigmoidf_(og);
        float cc = tanhf(cg), m = sigmoidf_(mg);
        float cold = c[(long)b * H_ + j];
        float r = ret[j];
        float cn = f * cold + i * cc;
        cn = cn * r + (1.f - r) * cold;
        cn = m * cn + (1.f - m) * cold;
        c[(long)b * H_ + j] = cn;
        o_[u] = o; cn_[u] = cn;
        s += o; s2 += o * o;
    }
    block_reduce2(s, s2, red);
    float mean = s * (1.f / H_);
    float var = s2 * (1.f / H_) - mean * mean;
    float rstd = rsqrtf(var + EPSF);

    float val[2];
    float s3 = 0.f, s4 = 0.f;
    #pragma unroll
    for (int u = 0; u < 2; ++u) {
        int j = tid + u * 256;
        float on = (o_[u] - mean) * rstd * elg[j] + elb[j];
        float oe = sigmoidf_(on);
        float v = oe * tanhf(cn_[u]);
        val[u] = v; s3 += v; s4 += v * v;
    }
    block_reduce2(s3, s4, red);
    float mean2 = s3 * (1.f / H_);
    float var2 = s4 * (1.f / H_) - mean2 * mean2;
    float rstd2 = rsqrtf(var2 + EPSF);
    #pragma unroll
    for (int u = 0; u < 2; ++u) {
        int j = tid + u * 256;
        float h = (val[u] - mean2) * rstd2 * lng[j] + lnb[j];
        hout[(long)b * hstride + j] = __float2bfloat16(h);
    }
}

__global__ __launch_bounds__(256)
void gate_ew(const __hip_bfloat16* __restrict__ g, float* __restrict__ c,
             const float* __restrict__ ret,
             const float* __restrict__ elg, const float* __restrict__ elb,
             const float* __restrict__ lng, const float* __restrict__ lnb,
             __hip_bfloat16* __restrict__ hout, long hstride) {
    gate_ew_body(g, c, ret, elg, elb, lng, lnb, hout, hstride, blockIdx.x);
}

__global__ __launch_bounds__(256)
void gate_ew_dual(const __hip_bfloat16* ga, float* ca, const float* reta,
                  const float* elga, const float* elba,
                  const float* lnga, const float* lnba,
                  __hip_bfloat16* houta, long hstridea,
                  const __hip_bfloat16* gb, float* cb, const float* retb,
                  const float* elgb, const float* elbb,
                  const float* lngb, const float* lnbb,
                  __hip_bfloat16* houtb, long hstrideb) {
    int bid = blockIdx.x;
    bool isB = bid >= B_;
    int b = isB ? bid - B_ : bid;
    const __hip_bfloat16* g = isB ? gb : ga;
    float* c        = isB ? cb : ca;
    const float* ret = isB ? retb : reta;
    const float* elg = isB ? elgb : elga;
    const float* elb = isB ? elbb : elba;
    const float* lng = isB ? lngb : lnga;
    const float* lnb = isB ? lnbb : lnba;
    __hip_bfloat16* hout = isB ? houtb : houta;
    long hstride = isB ? hstrideb : hstridea;
    gate_ew_body(g, c, ret, elg, elb, lng, lnb, hout, hstride, b);
}

// ---------------------------------------------------------------------------
// R11 fused attention: occupancy-first rewrite (conservative codegen).
// Per block = one b. Wave h owns head h, lane owns 8 cols.
// Phase 1: scores -> 480 B LDS (coalesced global seq reads).
// Phase 2 (one barrier): per-lane softmax stats from LDS broadcasts; weights
// recomputed as exp(s-mx) on the fly (no p[30] register array).
// seq read twice from global; second pass is L2-hot (30 KB/row).
// R9 version: VGPR=144, LDS=34KB, Occ=11%, 138 us, all pipes <21%.
// ---------------------------------------------------------------------------
__global__ __launch_bounds__(256)
void attn_fused(const __hip_bfloat16* __restrict__ seq,
                const __hip_bfloat16* __restrict__ U,
                __hip_bfloat16* __restrict__ sbar) {
    const int b = blockIdx.x, tid = threadIdx.x;
    const int h = tid >> 6, lane = tid & 63;
    const int c0 = lane * 8;
    __shared__ float ps[NH_ * TT];      // 480 B
    const float scale = 0.08838834764831845f;   // 1/sqrt(128)

    float uq[8];
    {
        bf16x8 uv = *(const bf16x8*)&U[(size_t)b * (NH_ * H_) + h * H_ + c0];
        for (int j = 0; j < 8; ++j) uq[j] = bf2f(uv[j]);
    }
    const __hip_bfloat16* srow = seq + (size_t)b * TT * H_;

    for (int t = 0; t < TT; ++t) {
        bf16x8 sv = *(const bf16x8*)&srow[t * H_ + c0];
        float a = 0.f;
        for (int j = 0; j < 8; ++j) a += uq[j] * bf2f(sv[j]);
        a += __shfl_xor(a, 32);
        a += __shfl_xor(a, 16);
        a += __shfl_xor(a, 8);
        a += __shfl_xor(a, 4);
        a += __shfl_xor(a, 2);
        a += __shfl_xor(a, 1);
        if (lane == 0) ps[h * TT + t] = a * scale;
    }
    __syncthreads();

    float mx = -1e30f;
    for (int t = 0; t < TT; ++t) mx = fmaxf(mx, ps[h * TT + t]);
    float den = 0.f;
    for (int t = 0; t < TT; ++t) den += __expf(ps[h * TT + t] - mx);
    float inv = 1.f / den;

    float accv[8];
    for (int j = 0; j < 8; ++j) accv[j] = 0.f;
    for (int t = 0; t < TT; ++t) {
        float w = __expf(ps[h * TT + t] - mx) * inv;
        bf16x8 sv = *(const bf16x8*)&srow[t * H_ + c0];
        for (int j = 0; j < 8; ++j) accv[j] += w * bf2f(sv[j]);
    }
    bf16x8 outv;
    for (int j = 0; j < 8; ++j) {
        __hip_bfloat16 hv = __float2bfloat16(accv[j]);
        outv[j] = *(short*)&hv;
    }
    *(bf16x8*)&sbar[(size_t)b * (NH_ * H_) + h * H_ + c0] = outv;
}

// ---------------------------------------------------------------------------
// Head: bn2 on latent then out (128->14). One block (128 thr) per batch row.
// ---------------------------------------------------------------------------
__global__ __launch_bounds__(128)
void head_kernel(const float* __restrict__ lat_in,
                 const float* __restrict__ g2, const float* __restrict__ b2,
                 const float* __restrict__ rm2, const float* __restrict__ rv2,
                 const float* __restrict__ ow, const float* __restrict__ ob,
                 float* __restrict__ out) {
    const int b = blockIdx.x, tid = threadIdx.x;
    __shared__ float ls[LAT_];
    float a = lat_in[(long)b * LAT_ + tid];
    ls[tid] = (a - rm2[tid]) * rsqrtf(rv2[tid] + EPSF) * g2[tid] + b2[tid];
    __syncthreads();
    if (tid < OUT_) {
        float acc = ob[tid];
        #pragma unroll 4
        for (int j = 0; j < LAT_; ++j) acc += ls[j] * ow[tid * LAT_ + j];
        out[(long)b * OUT_ + tid] = acc;
    }
}

// ---------------------------------------------------------------------------
extern "C" void kernel_launch(void* const* d_in, const int* in_sizes, int n_in,
                              void* d_out, int out_size, void* d_ws, size_t ws_size,
                              hipStream_t stream) {
    const float* x        = (const float*)d_in[0];
    const float* conv1_w  = (const float*)d_in[1];
    const float* conv1_b  = (const float*)d_in[2];
    const float* bn1_g    = (const float*)d_in[3];
    const float* bn1_b    = (const float*)d_in[4];
    const float* bn1_rm   = (const float*)d_in[5];
    const float* bn1_rv   = (const float*)d_in[6];
    const float* comp_w   = (const float*)d_in[7];
    const float* comp_b   = (const float*)d_in[8];
    const float* proj_w   = (const float*)d_in[9];
    const float* proj_b   = (const float*)d_in[10];
    const float* gates_w  = (const float*)d_in[11];
    const float* gates_b  = (const float*)d_in[12];
    const float* retention= (const float*)d_in[13];
    const float* expln_g  = (const float*)d_in[14];
    const float* expln_b  = (const float*)d_in[15];
    const float* ln_g     = (const float*)d_in[16];
    const float* ln_b     = (const float*)d_in[17];
    const float* attn_in_w  = (const float*)d_in[18];
    const float* attn_in_b  = (const float*)d_in[19];
    const float* attn_out_w = (const float*)d_in[20];
    const float* attn_out_b = (const float*)d_in[21];
    const float* bneck_w  = (const float*)d_in[22];
    const float* bneck_b  = (const float*)d_in[23];
    const float* bn2_g    = (const float*)d_in[24];
    const float* bn2_b    = (const float*)d_in[25];
    const float* bn2_rm   = (const float*)d_in[26];
    const float* bn2_rv   = (const float*)d_in[27];
    const float* out_w    = (const float*)d_in[28];
    const float* out_b    = (const float*)d_in[29];
    float* out = (float*)d_out;

    // ---- workspace layout (~220 MiB) ----
    char* base = (char*)d_ws;
    size_t off = 0;
    auto alloc = [&](size_t nbytes) -> char* {
        char* p = base + off;
        off += (nbytes + 255) & ~(size_t)255;
        return p;
    };
    __hip_bfloat16* seq_bf = (__hip_bfloat16*)alloc((size_t)B_ * TT * H_ * 2);   // 126 MB
    // union (42 MB): feat / 2x gate buffers (scan) / U+sbar+wkd+wvd (attn)
    size_t g_bytes = (size_t)B_ * NGATE_ * 2;                                    // 21 MB
    char* un = alloc(2 * g_bytes);
    __hip_bfloat16* feat_bf = (__hip_bfloat16*)un;
    __hip_bfloat16* gA_bf   = (__hip_bfloat16*)un;
    __hip_bfloat16* gB_bf   = (__hip_bfloat16*)(un + g_bytes);
    __hip_bfloat16* U_bf    = (__hip_bfloat16*)un;                               // 16 MB
    __hip_bfloat16* sbar_bf = (__hip_bfloat16*)(un + (size_t)16 * 1024 * 1024);  // 16 MB
    __hip_bfloat16* wkd_bf  = (__hip_bfloat16*)(un + (size_t)32 * 1024 * 1024);  // 2 MB
    __hip_bfloat16* wvd_bf  = (__hip_bfloat16*)(un + (size_t)35 * 1024 * 1024);  // 2 MB
    float*          c0    = (float*)alloc((size_t)B_ * H_ * 4);
    float*          c1    = (float*)alloc((size_t)B_ * H_ * 4);
    __hip_bfloat16* h0_bf = (__hip_bfloat16*)alloc((size_t)B_ * H_ * 2);
    __hip_bfloat16* q_bf  = (__hip_bfloat16*)alloc((size_t)B_ * H_ * 2);  // also fin
    __hip_bfloat16* fin_bf = q_bf;
    __hip_bfloat16* av_bf = (__hip_bfloat16*)alloc((size_t)B_ * H_ * 2);
    float*          lat_f = (float*)alloc((size_t)B_ * LAT_ * 4);
    __hip_bfloat16* gw_bf = (__hip_bfloat16*)alloc((size_t)L_ * 5 * H_ * 2 * H_ * 2);
    __hip_bfloat16* ai_bf = (__hip_bfloat16*)alloc((size_t)H_ * H_ * 2);  // q rows only
    __hip_bfloat16* ao_bf = (__hip_bfloat16*)alloc((size_t)H_ * H_ * 2);
    __hip_bfloat16* pw_bf = (__hip_bfloat16*)alloc((size_t)H_ * FEATK * 2);
    __hip_bfloat16* bw_bf = (__hip_bfloat16*)alloc((size_t)LAT_ * H_ * 2);
    (void)ws_size; (void)in_sizes; (void)n_in; (void)out_size;

    // ---- weight conversion + state zeroing ----
    cvt_bf16<<<2048, 256, 0, stream>>>(gates_w, gw_bf, (long)L_ * 5 * H_ * 2 * H_);
    cvt_bf16<<<256, 256, 0, stream>>>(attn_in_w, ai_bf, (long)H_ * H_);
    cvt_bf16<<<256, 256, 0, stream>>>(attn_out_w, ao_bf, (long)H_ * H_);
    cvt_bf16<<<64, 256, 0, stream>>>(bneck_w, bw_bf, (long)LAT_ * H_);
    pad_projw<<<(H_ * FEATK + 255) / 256, 256, 0, stream>>>(proj_w, pw_bf);
    zero_f32<<<2048, 256, 0, stream>>>(c0, (long)2 * B_ * H_);

    // ---- front-end: feat, then proj via MFMA GEMM ----
    frontend_kernel<<<B_, 256, 0, stream>>>(x, conv1_w, conv1_b, bn1_g, bn1_b, bn1_rm,
                                            bn1_rv, comp_w, comp_b, feat_bf);
    gemm_bias<1><<<dim3(H_ / 128, (B_ * TT) / 128), 256, 0, stream>>>(
        feat_bf, FEATK, (const __hip_bfloat16*)nullptr, 0, FEATK,
        pw_bf, FEATK, proj_b, (void*)seq_bf, H_, FEATK);

    // ---- recurrent scan (layer1(t) || layer0(t+1) dual pipeline) ----
    const int WL = 5 * H_ * 2 * H_;
    const dim3 ggrid(NGATE_ / 128, B_ / 128);

    gemm_bias<1><<<ggrid, 256, 0, stream>>>(
        seq_bf, TT * H_, (const __hip_bfloat16*)nullptr, 0, H_,
        gw_bf, 2 * H_, gates_b, (void*)gB_bf, NGATE_, H_);
    gate_ew<<<B_, 256, 0, stream>>>(gB_bf, c0, retention, expln_g, expln_b,
                                    ln_g, ln_b, h0_bf, H_);

    for (int t = 0; t < TT - 1; ++t) {
        gemm_dual_db<1><<<1280, 256, 0, stream>>>(
            h0_bf, H_, (t == 0) ? (const __hip_bfloat16*)nullptr
                                : seq_bf + (size_t)(t - 1) * H_,
            TT * H_, (t == 0) ? H_ : 2 * H_, gw_bf + WL, gates_b + NGATE_, (void*)gA_bf,
            seq_bf + (size_t)(t + 1) * H_, TT * H_, h0_bf, H_, 2 * H_,
            gw_bf, gates_b, (void*)gB_bf,
            H_, 2 * H_, NGATE_);
        gate_ew_dual<<<2 * B_, 256, 0, stream>>>(
            gA_bf, c1, retention + H_, expln_g + H_, expln_b + H_,
            ln_g + H_, ln_b + H_, seq_bf + (size_t)t * H_, TT * H_,
            gB_bf, c0, retention, expln_g, expln_b,
            ln_g, ln_b, h0_bf, H_);
    }
    gemm_bias<1><<<ggrid, 256, 0, stream>>>(
        h0_bf, H_, seq_bf + (size_t)(TT - 2) * H_, TT * H_, H_,
        gw_bf + WL, 2 * H_, gates_b + NGATE_, (void*)gA_bf, NGATE_, 2 * H_);
    gate_ew<<<B_, 256, 0, stream>>>(gA_bf, c1, retention + H_, expln_g + H_,
                                    expln_b + H_, ln_g + H_, ln_b + H_,
                                    seq_bf + (size_t)(TT - 1) * H_, TT * H_);

    // ---- attention (restructured): build block-diag weights in freed union ----
    build_wkd<<<4096, 256, 0, stream>>>(attn_in_w, wkd_bf);
    build_wvd<<<4096, 256, 0, stream>>>(attn_in_w, wvd_bf);

    // q projection (last timestep) -> bf16
    gemm_bias<1><<<dim3(H_ / 128, B_ / 128), 256, 0, stream>>>(
        seq_bf + (size_t)29 * H_, TT * H_, (const __hip_bfloat16*)nullptr, 0, H_,
        ai_bf, H_, attn_in_b, (void*)q_bf, H_, H_);

    // U = q @ wkd^T  [4096, 2048]
    gemm_bias<1><<<dim3(2048 / 128, B_ / 128), 256, 0, stream>>>(
        q_bf, H_, (const __hip_bfloat16*)nullptr, 0, H_,
        wkd_bf, H_, (const float*)nullptr, (void*)U_bf, 2048, H_);

    // fused scores/softmax/weighted-sum -> sbar [4096, 2048]
    attn_fused<<<B_, 256, 0, stream>>>(seq_bf, U_bf, sbar_bf);

    // o = sbar @ wvd^T + bv -> av [4096, 512]
    gemm_bias<1><<<dim3(H_ / 128, B_ / 128), 256, 0, stream>>>(
        sbar_bf, 2048, (const __hip_bfloat16*)nullptr, 0, 2048,
        wvd_bf, 2048, attn_in_b + 2 * H_, (void*)av_bf, H_, 2048);

    // attn_out projection -> bf16 fin (aliases q_bf; q fully consumed)
    gemm_bias<1><<<dim3(H_ / 128, B_ / 128), 256, 0, stream>>>(
        av_bf, H_, (const __hip_bfloat16*)nullptr, 0, H_,
        ao_bf, H_, attn_out_b, (void*)fin_bf, H_, H_);

    // ---- bneck GEMM -> latent f32, then bn2+head ----
    gemm_bias<0><<<dim3(LAT_ / 128, B_ / 128), 256, 0, stream>>>(
        fin_bf, H_, (const __hip_bfloat16*)nullptr, 0, H_,
        bw_bf, H_, bneck_b, (void*)lat_f, LAT_, H_);
    head_kernel<<<B_, 128, 0, stream>>>(lat_f, bn2_g, bn2_b, bn2_rm, bn2_rv,
                                        out_w, out_b, out);
}